// Round 5
// baseline (832.043 us; speedup 1.0000x reference)
//
#include <hip/hip_runtime.h>
#include <hip/hip_fp16.h>

#define HID 128
#define ELLW 64
#define BSH 7              // bucket shift: 128 nodes per bucket
#define BCAP 2600          // bucket capacity (mean 2046, sd ~45 -> 12 sigma margin)
#define OVF_CAP 8192

struct alignas(8) Half4 { __half2 lo, hi; };

// ---------------- bucketed ELL build ----------------

__global__ void k_zero_ints(int* p, int n) {
  int i = blockIdx.x * blockDim.x + threadIdx.x;
  if (i < n) p[i] = 0;
}

// pass 1: partition edges into buckets of 128 consecutive dst nodes
__global__ void k_bucket4(const int4* __restrict__ src4, const int4* __restrict__ dst4,
                          int* bcnt, unsigned* __restrict__ bk, int* ovfn,
                          int2* __restrict__ ovf, int E4) {
  int t = blockIdx.x * blockDim.x + threadIdx.x;
  if (t >= E4) return;
  int4 d = dst4[t];
  int4 s = src4[t];
  int b0 = d.x >> BSH, b1 = d.y >> BSH, b2 = d.z >> BSH, b3 = d.w >> BSH;
  int p0 = atomicAdd(&bcnt[b0], 1);
  int p1 = atomicAdd(&bcnt[b1], 1);
  int p2 = atomicAdd(&bcnt[b2], 1);
  int p3 = atomicAdd(&bcnt[b3], 1);
  if (p0 < BCAP) bk[(size_t)b0 * BCAP + p0] = ((unsigned)s.x << BSH) | (d.x & 127);
  else { int q = atomicAdd(ovfn, 1); if (q < OVF_CAP) ovf[q] = make_int2(s.x, d.x); }
  if (p1 < BCAP) bk[(size_t)b1 * BCAP + p1] = ((unsigned)s.y << BSH) | (d.y & 127);
  else { int q = atomicAdd(ovfn, 1); if (q < OVF_CAP) ovf[q] = make_int2(s.y, d.y); }
  if (p2 < BCAP) bk[(size_t)b2 * BCAP + p2] = ((unsigned)s.z << BSH) | (d.z & 127);
  else { int q = atomicAdd(ovfn, 1); if (q < OVF_CAP) ovf[q] = make_int2(s.z, d.z); }
  if (p3 < BCAP) bk[(size_t)b3 * BCAP + p3] = ((unsigned)s.w << BSH) | (d.w & 127);
  else { int q = atomicAdd(ovfn, 1); if (q < OVF_CAP) ovf[q] = make_int2(s.w, d.w); }
}

__global__ void k_bucket1(const int* __restrict__ src, const int* __restrict__ dst,
                          int* bcnt, unsigned* __restrict__ bk, int* ovfn,
                          int2* __restrict__ ovf, int E) {
  int e = blockIdx.x * blockDim.x + threadIdx.x;
  if (e >= E) return;
  int s = src[e], d = dst[e];
  int b = d >> BSH;
  int p = atomicAdd(&bcnt[b], 1);
  if (p < BCAP) bk[(size_t)b * BCAP + p] = ((unsigned)s << BSH) | (d & 127);
  else { int q = atomicAdd(ovfn, 1); if (q < OVF_CAP) ovf[q] = make_int2(s, d); }
}

// pass 2: one block per bucket; LDS cursors; writes ELL rows + cnt
__global__ __launch_bounds__(256) void k_ell_build(
    const unsigned* __restrict__ bk, const int* __restrict__ bcnt,
    int* __restrict__ ell, int* __restrict__ cnt, int N) {
  int b = blockIdx.x;
  int t = threadIdx.x;
  __shared__ int lcnt[128];
  if (t < 128) lcnt[t] = 0;
  __syncthreads();
  int n = bcnt[b]; if (n > BCAP) n = BCAP;
  const unsigned* my = bk + (size_t)b * BCAP;
  for (int k = t; k < n; k += 256) {
    unsigned r = my[k];
    int d0 = r & 127;
    int s = (int)(r >> BSH);
    int p = atomicAdd(&lcnt[d0], 1);
    if (p < ELLW) ell[((size_t)(b * 128 + d0)) * ELLW + p] = s;
  }
  __syncthreads();
  int node = b * 128 + t;
  if (t < 128 && node < N) cnt[node] = lcnt[t];
}

// pass 3: overflow edges (normally zero)
__global__ void k_ovf_build(const int2* __restrict__ ovf, const int* __restrict__ ovfn,
                            int* cnt, int* ell) {
  int n = *ovfn; if (n > OVF_CAP) n = OVF_CAP;
  for (int k = threadIdx.x; k < n; k += blockDim.x) {
    int2 e = ovf[k];
    int p = atomicAdd(&cnt[e.y], 1);
    if (p < ELLW) ell[(size_t)e.y * ELLW + p] = e.x;
  }
}

__global__ void k_dis(const int* __restrict__ cnt, float* dis, int N) {
  int i = blockIdx.x * blockDim.x + threadIdx.x;
  if (i < N) dis[i] = rsqrtf((float)(cnt[i] + 1));
}

// ---------------- layer 0: aggregate 3-dim x first, then transform ----------------

__global__ void k_prep_x(const float* __restrict__ x, const float* __restrict__ dis,
                         float4* __restrict__ x4, int N) {
  int i = blockIdx.x * blockDim.x + threadIdx.x;
  if (i >= N) return;
  float s = dis[i];
  x4[i] = make_float4(s * x[i * 3 + 0], s * x[i * 3 + 1], s * x[i * 3 + 2], 0.f);
}

__global__ void k_agg3(const float4* __restrict__ x4, const int* __restrict__ ell,
                       const int* __restrict__ cnt, const float* __restrict__ dis,
                       float4* __restrict__ z4, int N) {
  int i = blockIdx.x * blockDim.x + threadIdx.x;
  if (i >= N) return;
  float4 a = x4[i];  // self-loop
  int c = cnt[i]; if (c > ELLW) c = ELLW;
  const int* row = &ell[(size_t)i * ELLW];
  for (int k = 0; k < c; ++k) {
    float4 v = x4[row[k]];
    a.x += v.x; a.y += v.y; a.z += v.z;
  }
  float s = dis[i];
  z4[i] = make_float4(s * a.x, s * a.y, s * a.z, 0.f);
}

__global__ void k_gemm3b(const float4* __restrict__ z4, const float* __restrict__ W0,
                         const float* __restrict__ b0, float* __restrict__ h, int N) {
  int tid = blockIdx.x * blockDim.x + threadIdx.x;
  int i = tid >> 5, q = tid & 31;
  if (i >= N) return;
  float4 z = z4[i];
  float4 w0 = *(const float4*)&W0[0 * HID + q * 4];
  float4 w1 = *(const float4*)&W0[1 * HID + q * 4];
  float4 w2 = *(const float4*)&W0[2 * HID + q * 4];
  float4 bb = *(const float4*)&b0[q * 4];
  float4 o;
  o.x = fmaxf(z.x * w0.x + z.y * w1.x + z.z * w2.x + bb.x, 0.f);
  o.y = fmaxf(z.x * w0.y + z.y * w1.y + z.z * w2.y + bb.y, 0.f);
  o.z = fmaxf(z.x * w0.z + z.y * w1.z + z.z * w2.z + bb.z, 0.f);
  o.w = fmaxf(z.x * w0.w + z.y * w1.w + z.z * w2.w + bb.w, 0.f);
  *(float4*)&h[(size_t)i * HID + q * 4] = o;
}

// ---------------- GEMM 128x128, fp16 output with dis folded ----------------

#define GR 64
__global__ __launch_bounds__(256) void k_gemm128h(
    const float* __restrict__ H, const float* __restrict__ W,
    const float* __restrict__ dis, __half* __restrict__ G16, int N) {
  __shared__ float Ws[128 * 128];   // [k][c]
  __shared__ float Hs[128 * 68];    // [k][r], padded
  int t = threadIdx.x;
  int r0 = blockIdx.x * GR;
  const float4* W4 = (const float4*)W;
  float4* Ws4 = (float4*)Ws;
#pragma unroll
  for (int i = 0; i < 16; ++i) Ws4[t + i * 256] = W4[t + i * 256];
#pragma unroll
  for (int i = 0; i < 8; ++i) {
    int idx = t + i * 256;
    int r = idx >> 5;
    int k4 = idx & 31;
    int row = r0 + r;
    float4 v = make_float4(0.f, 0.f, 0.f, 0.f);
    if (row < N) v = *(const float4*)&H[(size_t)row * HID + k4 * 4];
    Hs[(k4 * 4 + 0) * 68 + r] = v.x;
    Hs[(k4 * 4 + 1) * 68 + r] = v.y;
    Hs[(k4 * 4 + 2) * 68 + r] = v.z;
    Hs[(k4 * 4 + 3) * 68 + r] = v.w;
  }
  __syncthreads();
  int rt = t >> 5;
  int ct = t & 31;
  float acc[8][4];
#pragma unroll
  for (int r = 0; r < 8; ++r)
#pragma unroll
    for (int c = 0; c < 4; ++c) acc[r][c] = 0.f;
  for (int k = 0; k < 128; ++k) {
    float4 h0 = *(const float4*)&Hs[k * 68 + rt * 8];
    float4 h1 = *(const float4*)&Hs[k * 68 + rt * 8 + 4];
    float4 wv = *(const float4*)&Ws[k * 128 + ct * 4];
    float hh[8] = {h0.x, h0.y, h0.z, h0.w, h1.x, h1.y, h1.z, h1.w};
    float ww[4] = {wv.x, wv.y, wv.z, wv.w};
#pragma unroll
    for (int r = 0; r < 8; ++r)
#pragma unroll
      for (int c = 0; c < 4; ++c) acc[r][c] += hh[r] * ww[c];
  }
#pragma unroll
  for (int r = 0; r < 8; ++r) {
    int row = r0 + rt * 8 + r;
    if (row < N) {
      float s = dis[row];
      Half4 o;
      o.lo = __float22half2_rn(make_float2(s * acc[r][0], s * acc[r][1]));
      o.hi = __float22half2_rn(make_float2(s * acc[r][2], s * acc[r][3]));
      *(Half4*)&G16[(size_t)row * HID + ct * 4] = o;
    }
  }
}

// ---------------- fused gather (fp16 payload) + finalize ----------------

__global__ __launch_bounds__(256) void k_gather16(
    const __half* __restrict__ g16, const int* __restrict__ ell,
    const int* __restrict__ cnt, const float* __restrict__ dis,
    const float* __restrict__ b, float* __restrict__ h, int N) {
  int tid = blockIdx.x * blockDim.x + threadIdx.x;
  int i = tid >> 5, q = tid & 31;
  if (i >= N) return;
  Half4 v0 = *(const Half4*)&g16[(size_t)i * HID + q * 4];  // self-loop
  float2 f0 = __half22float2(v0.lo), f1 = __half22float2(v0.hi);
  float4 acc = make_float4(f0.x, f0.y, f1.x, f1.y);
  int c = cnt[i]; if (c > ELLW) c = ELLW;
  const int* row = &ell[(size_t)i * ELLW];
  for (int k = 0; k < c; ++k) {
    int s = row[k];
    Half4 v = *(const Half4*)&g16[(size_t)s * HID + q * 4];
    float2 a = __half22float2(v.lo), d = __half22float2(v.hi);
    acc.x += a.x; acc.y += a.y; acc.z += d.x; acc.w += d.y;
  }
  float sc = dis[i];
  float4 bb = *(const float4*)&b[q * 4];
  float4 o = make_float4(fmaxf(sc * acc.x + bb.x, 0.f), fmaxf(sc * acc.y + bb.y, 0.f),
                         fmaxf(sc * acc.z + bb.z, 0.f), fmaxf(sc * acc.w + bb.w, 0.f));
  *(float4*)&h[(size_t)i * HID + q * 4] = o;
}

// ---------------- fused pool + MLP ----------------

__device__ __forceinline__ int lower_bound_i(const int* __restrict__ a, int n, int v) {
  int lo = 0, hi = n;
  while (lo < hi) {
    int m = (lo + hi) >> 1;
    if (a[m] < v) lo = m + 1; else hi = m;
  }
  return lo;
}

__global__ __launch_bounds__(256) void k_pool_mlp(
    const float* __restrict__ h, const int* __restrict__ batch, int N,
    const float* __restrict__ Wf1, const float* __restrict__ bf1,
    const float* __restrict__ Wf2, const float* __restrict__ bf2,
    float* __restrict__ out) {
  int g = blockIdx.x;
  int t = threadIdx.x;
  int lo = lower_bound_i(batch, N, g);
  int hi = lower_bound_i(batch, N, g + 1);

  __shared__ float4 part4[256];
  __shared__ float pooled[128];
  __shared__ float dense[64];

  int col4 = t & 31;
  int roff = t >> 5;
  float4 s = make_float4(0.f, 0.f, 0.f, 0.f);
  for (int r = lo + roff; r < hi; r += 8) {
    float4 v = *(const float4*)&h[(size_t)r * HID + col4 * 4];
    s.x += v.x; s.y += v.y; s.z += v.z; s.w += v.w;
  }
  part4[roff * 32 + col4] = s;
  __syncthreads();

  float inv = 1.0f / fmaxf((float)(hi - lo), 1.0f);
  if (t < 32) {
    float4 tot = part4[t];
#pragma unroll
    for (int j = 1; j < 8; ++j) {
      float4 v = part4[j * 32 + t];
      tot.x += v.x; tot.y += v.y; tot.z += v.z; tot.w += v.w;
    }
    pooled[t * 4 + 0] = tot.x * inv;
    pooled[t * 4 + 1] = tot.y * inv;
    pooled[t * 4 + 2] = tot.z * inv;
    pooled[t * 4 + 3] = tot.w * inv;
  }
  __syncthreads();

  if (t < 64) {
    float a = bf1[t];
    for (int k = 0; k < 128; ++k) a += pooled[k] * Wf1[k * 64 + t];
    dense[t] = fmaxf(a, 0.f);
  }
  __syncthreads();

  if (t < 64) {
    float prod = dense[t] * Wf2[t];
#pragma unroll
    for (int off = 32; off; off >>= 1) prod += __shfl_down(prod, off);
    if (t == 0) out[g] = prod + bf2[0];
  }
}

// ---------------- launch ----------------

static inline size_t align256(size_t x) { return (x + 255) & ~(size_t)255; }

extern "C" void kernel_launch(void* const* d_in, const int* in_sizes, int n_in,
                              void* d_out, int out_size, void* d_ws, size_t ws_size,
                              hipStream_t stream) {
  const float* x = (const float*)d_in[0];
  const int* ei = (const int*)d_in[1];
  const int* batch = (const int*)d_in[2];
  const float* W0 = (const float*)d_in[3];
  const float* b0 = (const float*)d_in[4];
  const float* W1 = (const float*)d_in[5];
  const float* b1 = (const float*)d_in[6];
  const float* W2 = (const float*)d_in[7];
  const float* b2 = (const float*)d_in[8];
  const float* Wf1 = (const float*)d_in[9];
  const float* bf1 = (const float*)d_in[10];
  const float* Wf2 = (const float*)d_in[11];
  const float* bf2 = (const float*)d_in[12];
  float* out = (float*)d_out;

  const int N = in_sizes[0] / 3;
  const int E = in_sizes[1] / 2;
  const int Gn = out_size;
  const int nbuk = (N + 127) >> BSH;

  const int* src = ei;
  const int* dst = ei + E;

  char* ws = (char*)d_ws;
  size_t o = 0;
  int* cnt = (int*)(ws + o); o = align256(o + (size_t)N * 4);
  float* dis = (float*)(ws + o); o = align256(o + (size_t)N * 4);
  float4* x4 = (float4*)(ws + o); o = align256(o + (size_t)N * 16);
  float4* z4 = (float4*)(ws + o); o = align256(o + (size_t)N * 16);
  int* ell = (int*)(ws + o); o = align256(o + (size_t)N * ELLW * 4);
  __half* g16 = (__half*)(ws + o); o = align256(o + (size_t)N * HID * 2);
  float* h = (float*)(ws + o); o = align256(o + (size_t)N * HID * 4);
  int* bcnt = (int*)(ws + o); o = align256(o + (size_t)(nbuk + 1) * 4);
  int* ovfn = bcnt + nbuk;  // overflow counter is last slot
  unsigned* bk = (unsigned*)(ws + o); o = align256(o + (size_t)nbuk * BCAP * 4);
  int2* ovf = (int2*)(ws + o); o = align256(o + (size_t)OVF_CAP * 8);

  const int BS = 256;
  int gN = (N + BS - 1) / BS;
  int gN32 = (int)(((long long)N * 32 + BS - 1) / BS);

  // ---- bucketed ELL build ----
  k_zero_ints<<<(nbuk + 1 + BS - 1) / BS, BS, 0, stream>>>(bcnt, nbuk + 1);
  bool vec4ok = (E % 4 == 0) && (((uintptr_t)src & 15) == 0) && (((uintptr_t)dst & 15) == 0);
  if (vec4ok) {
    int E4 = E / 4;
    k_bucket4<<<(E4 + BS - 1) / BS, BS, 0, stream>>>((const int4*)src, (const int4*)dst,
                                                     bcnt, bk, ovfn, ovf, E4);
  } else {
    k_bucket1<<<(E + BS - 1) / BS, BS, 0, stream>>>(src, dst, bcnt, bk, ovfn, ovf, E);
  }
  k_ell_build<<<nbuk, 256, 0, stream>>>(bk, bcnt, ell, cnt, N);
  k_ovf_build<<<1, 256, 0, stream>>>(ovf, ovfn, cnt, ell);
  k_dis<<<gN, BS, 0, stream>>>(cnt, dis, N);

  // ---- layer 0: aggregate 3-dim x, then transform ----
  k_prep_x<<<gN, BS, 0, stream>>>(x, dis, x4, N);
  k_agg3<<<gN, BS, 0, stream>>>(x4, ell, cnt, dis, z4, N);
  k_gemm3b<<<gN32, BS, 0, stream>>>(z4, W0, b0, h, N);

  // ---- layer 1 ----
  k_gemm128h<<<(N + GR - 1) / GR, 256, 0, stream>>>(h, W1, dis, g16, N);
  k_gather16<<<gN32, BS, 0, stream>>>(g16, ell, cnt, dis, b1, h, N);

  // ---- layer 2 ----
  k_gemm128h<<<(N + GR - 1) / GR, 256, 0, stream>>>(h, W2, dis, g16, N);
  k_gather16<<<gN32, BS, 0, stream>>>(g16, ell, cnt, dis, b2, h, N);

  // ---- fused pool + MLP ----
  k_pool_mlp<<<Gn, 256, 0, stream>>>(h, batch, N, Wf1, bf1, Wf2, bf2, out);
}

// Round 6
// 476.180 us; speedup vs baseline: 1.7473x; 1.7473x over previous
//
#include <hip/hip_runtime.h>

#define HID 128
#define ELLW 64

typedef _Float16 half8 __attribute__((ext_vector_type(8)));
typedef float f32x4 __attribute__((ext_vector_type(4)));
struct alignas(8) H4v { _Float16 x, y, z, w; };

// ---------------- ELL build (direct, single atomic pass; cnt = in-degree) ----------------

__global__ void k_zero_cnt(int* cnt, int N) {
  int i = blockIdx.x * blockDim.x + threadIdx.x;
  if (i < N) cnt[i] = 0;
}

__global__ void k_fill_ell4(const int4* __restrict__ src4, const int4* __restrict__ dst4,
                            int* cnt, int* ell, int E4) {
  int t = blockIdx.x * blockDim.x + threadIdx.x;
  if (t >= E4) return;
  int4 d = dst4[t];
  int4 s = src4[t];
  int p0 = atomicAdd(&cnt[d.x], 1);
  int p1 = atomicAdd(&cnt[d.y], 1);
  int p2 = atomicAdd(&cnt[d.z], 1);
  int p3 = atomicAdd(&cnt[d.w], 1);
  if (p0 < ELLW) ell[(size_t)d.x * ELLW + p0] = s.x;
  if (p1 < ELLW) ell[(size_t)d.y * ELLW + p1] = s.y;
  if (p2 < ELLW) ell[(size_t)d.z * ELLW + p2] = s.z;
  if (p3 < ELLW) ell[(size_t)d.w * ELLW + p3] = s.w;
}

__global__ void k_fill_ell1(const int* __restrict__ src, const int* __restrict__ dst,
                            int* cnt, int* ell, int E) {
  int e = blockIdx.x * blockDim.x + threadIdx.x;
  if (e < E) {
    int d = dst[e];
    int p = atomicAdd(&cnt[d], 1);
    if (p < ELLW) ell[(size_t)d * ELLW + p] = src[e];
  }
}

__global__ void k_dis(const int* __restrict__ cnt, float* dis, int N) {
  int i = blockIdx.x * blockDim.x + threadIdx.x;
  if (i < N) dis[i] = rsqrtf((float)(cnt[i] + 1));
}

// ---------------- layer 0: aggregate 3-dim x first, then transform ----------------

__global__ void k_prep_x(const float* __restrict__ x, const float* __restrict__ dis,
                         float4* __restrict__ x4, int N) {
  int i = blockIdx.x * blockDim.x + threadIdx.x;
  if (i >= N) return;
  float s = dis[i];
  x4[i] = make_float4(s * x[i * 3 + 0], s * x[i * 3 + 1], s * x[i * 3 + 2], 0.f);
}

__global__ void k_agg3(const float4* __restrict__ x4, const int* __restrict__ ell,
                       const int* __restrict__ cnt, const float* __restrict__ dis,
                       float4* __restrict__ z4, int N) {
  int i = blockIdx.x * blockDim.x + threadIdx.x;
  if (i >= N) return;
  float4 a = x4[i];  // self-loop
  int c = cnt[i]; if (c > ELLW) c = ELLW;
  const int* row = &ell[(size_t)i * ELLW];
  for (int k = 0; k < c; ++k) {
    float4 v = x4[row[k]];
    a.x += v.x; a.y += v.y; a.z += v.z;
  }
  float s = dis[i];
  z4[i] = make_float4(s * a.x, s * a.y, s * a.z, 0.f);
}

// h16[i,:] = relu(z4[i] @ W0 + b0)  (fp16 out)
__global__ void k_gemm3b(const float4* __restrict__ z4, const float* __restrict__ W0,
                         const float* __restrict__ b0, _Float16* __restrict__ h16, int N) {
  int tid = blockIdx.x * blockDim.x + threadIdx.x;
  int i = tid >> 5, q = tid & 31;
  if (i >= N) return;
  float4 z = z4[i];
  float4 w0 = *(const float4*)&W0[0 * HID + q * 4];
  float4 w1 = *(const float4*)&W0[1 * HID + q * 4];
  float4 w2 = *(const float4*)&W0[2 * HID + q * 4];
  float4 bb = *(const float4*)&b0[q * 4];
  H4v o;
  o.x = (_Float16)fmaxf(z.x * w0.x + z.y * w1.x + z.z * w2.x + bb.x, 0.f);
  o.y = (_Float16)fmaxf(z.x * w0.y + z.y * w1.y + z.z * w2.y + bb.y, 0.f);
  o.z = (_Float16)fmaxf(z.x * w0.z + z.y * w1.z + z.z * w2.z + bb.z, 0.f);
  o.w = (_Float16)fmaxf(z.x * w0.w + z.y * w1.w + z.z * w2.w + bb.w, 0.f);
  *(H4v*)&h16[(size_t)i * HID + q * 4] = o;
}

// ---------------- W -> fp16 transposed [n][k] ----------------

__global__ void k_prep_w16(const float* __restrict__ W, _Float16* __restrict__ Wt) {
  int idx = blockIdx.x * blockDim.x + threadIdx.x;  // over 128*128
  if (idx >= HID * HID) return;
  int k = idx >> 7, n = idx & 127;  // coalesced read over n
  Wt[n * HID + k] = (_Float16)W[idx];
}

// ---------------- MFMA GEMM: g16 = dis * (h16 @ W)  ----------------
// block 256 = 4 waves; each wave one 16-row M-tile; BM=64/block; N=128 full.

__global__ __launch_bounds__(256) void k_gemm16(
    const _Float16* __restrict__ H16, const _Float16* __restrict__ Wt16,
    const float* __restrict__ dis, _Float16* __restrict__ G16, int N) {
  int wid = threadIdx.x >> 6;        // 0..3
  int lane = threadIdx.x & 63;
  int m0 = blockIdx.x * 64 + wid * 16;
  int arow = m0 + (lane & 15);
  if (arow >= N) arow = N - 1;       // clamp; stores guarded
  int kg = lane >> 4;                // 0..3 (k-group)

  f32x4 acc[8];
#pragma unroll
  for (int nt = 0; nt < 8; ++nt) acc[nt] = (f32x4){0.f, 0.f, 0.f, 0.f};

  const _Float16* ap = H16 + (size_t)arow * HID + kg * 8;
  const _Float16* bp = Wt16 + (size_t)(lane & 15) * HID + kg * 8;
#pragma unroll
  for (int kt = 0; kt < 4; ++kt) {
    half8 a = *(const half8*)(ap + kt * 32);
#pragma unroll
    for (int nt = 0; nt < 8; ++nt) {
      half8 b = *(const half8*)(bp + (size_t)nt * 16 * HID + kt * 32);
      acc[nt] = __builtin_amdgcn_mfma_f32_16x16x32_f16(a, b, acc[nt], 0, 0, 0);
    }
  }

  int ccol = lane & 15;
#pragma unroll
  for (int j = 0; j < 4; ++j) {
    int row = m0 + kg * 4 + j;
    if (row < N) {
      float s = dis[row];
#pragma unroll
      for (int nt = 0; nt < 8; ++nt) {
        G16[(size_t)row * HID + nt * 16 + ccol] = (_Float16)(s * acc[nt][j]);
      }
    }
  }
}

// ---------------- fused gather (fp16 payload) + finalize (fp16 out) ----------------

__global__ __launch_bounds__(256) void k_gather16(
    const _Float16* __restrict__ g16, const int* __restrict__ ell,
    const int* __restrict__ cnt, const float* __restrict__ dis,
    const float* __restrict__ b, _Float16* __restrict__ h16, int N) {
  int tid = blockIdx.x * blockDim.x + threadIdx.x;
  int i = tid >> 5, q = tid & 31;
  if (i >= N) return;
  H4v v0 = *(const H4v*)&g16[(size_t)i * HID + q * 4];  // self-loop
  float4 acc = make_float4((float)v0.x, (float)v0.y, (float)v0.z, (float)v0.w);
  int c = cnt[i]; if (c > ELLW) c = ELLW;
  const int* row = &ell[(size_t)i * ELLW];
  for (int k = 0; k < c; ++k) {
    int s = row[k];
    H4v v = *(const H4v*)&g16[(size_t)s * HID + q * 4];
    acc.x += (float)v.x; acc.y += (float)v.y; acc.z += (float)v.z; acc.w += (float)v.w;
  }
  float sc = dis[i];
  float4 bb = *(const float4*)&b[q * 4];
  H4v o;
  o.x = (_Float16)fmaxf(sc * acc.x + bb.x, 0.f);
  o.y = (_Float16)fmaxf(sc * acc.y + bb.y, 0.f);
  o.z = (_Float16)fmaxf(sc * acc.z + bb.z, 0.f);
  o.w = (_Float16)fmaxf(sc * acc.w + bb.w, 0.f);
  *(H4v*)&h16[(size_t)i * HID + q * 4] = o;
}

// ---------------- fused pool + MLP (batch sorted -> per-graph ranges) ----------------

__device__ __forceinline__ int lower_bound_i(const int* __restrict__ a, int n, int v) {
  int lo = 0, hi = n;
  while (lo < hi) {
    int m = (lo + hi) >> 1;
    if (a[m] < v) lo = m + 1; else hi = m;
  }
  return lo;
}

__global__ __launch_bounds__(256) void k_pool_mlp(
    const _Float16* __restrict__ h16, const int* __restrict__ batch, int N,
    const float* __restrict__ Wf1, const float* __restrict__ bf1,
    const float* __restrict__ Wf2, const float* __restrict__ bf2,
    float* __restrict__ out) {
  int g = blockIdx.x;
  int t = threadIdx.x;
  int lo = lower_bound_i(batch, N, g);
  int hi = lower_bound_i(batch, N, g + 1);

  __shared__ float4 part4[256];
  __shared__ float pooled[128];
  __shared__ float dense[64];

  int col4 = t & 31;
  int roff = t >> 5;
  float4 s = make_float4(0.f, 0.f, 0.f, 0.f);
  for (int r = lo + roff; r < hi; r += 8) {
    H4v v = *(const H4v*)&h16[(size_t)r * HID + col4 * 4];
    s.x += (float)v.x; s.y += (float)v.y; s.z += (float)v.z; s.w += (float)v.w;
  }
  part4[roff * 32 + col4] = s;
  __syncthreads();

  float inv = 1.0f / fmaxf((float)(hi - lo), 1.0f);
  if (t < 32) {
    float4 tot = part4[t];
#pragma unroll
    for (int j = 1; j < 8; ++j) {
      float4 v = part4[j * 32 + t];
      tot.x += v.x; tot.y += v.y; tot.z += v.z; tot.w += v.w;
    }
    pooled[t * 4 + 0] = tot.x * inv;
    pooled[t * 4 + 1] = tot.y * inv;
    pooled[t * 4 + 2] = tot.z * inv;
    pooled[t * 4 + 3] = tot.w * inv;
  }
  __syncthreads();

  if (t < 64) {
    float a = bf1[t];
    for (int k = 0; k < 128; ++k) a += pooled[k] * Wf1[k * 64 + t];
    dense[t] = fmaxf(a, 0.f);
  }
  __syncthreads();

  if (t < 64) {
    float prod = dense[t] * Wf2[t];
#pragma unroll
    for (int off = 32; off; off >>= 1) prod += __shfl_down(prod, off);
    if (t == 0) out[g] = prod + bf2[0];
  }
}

// ---------------- launch ----------------

static inline size_t align256(size_t x) { return (x + 255) & ~(size_t)255; }

extern "C" void kernel_launch(void* const* d_in, const int* in_sizes, int n_in,
                              void* d_out, int out_size, void* d_ws, size_t ws_size,
                              hipStream_t stream) {
  const float* x = (const float*)d_in[0];
  const int* ei = (const int*)d_in[1];
  const int* batch = (const int*)d_in[2];
  const float* W0 = (const float*)d_in[3];
  const float* b0 = (const float*)d_in[4];
  const float* W1 = (const float*)d_in[5];
  const float* b1 = (const float*)d_in[6];
  const float* W2 = (const float*)d_in[7];
  const float* b2 = (const float*)d_in[8];
  const float* Wf1 = (const float*)d_in[9];
  const float* bf1 = (const float*)d_in[10];
  const float* Wf2 = (const float*)d_in[11];
  const float* bf2 = (const float*)d_in[12];
  float* out = (float*)d_out;

  const int N = in_sizes[0] / 3;
  const int E = in_sizes[1] / 2;
  const int Gn = out_size;

  const int* src = ei;
  const int* dst = ei + E;

  char* ws = (char*)d_ws;
  size_t o = 0;
  int* cnt = (int*)(ws + o); o = align256(o + (size_t)N * 4);
  float* dis = (float*)(ws + o); o = align256(o + (size_t)N * 4);
  float4* x4 = (float4*)(ws + o); o = align256(o + (size_t)N * 16);
  float4* z4 = (float4*)(ws + o); o = align256(o + (size_t)N * 16);
  int* ell = (int*)(ws + o); o = align256(o + (size_t)N * ELLW * 4);
  _Float16* g16 = (_Float16*)(ws + o); o = align256(o + (size_t)N * HID * 2);
  _Float16* h16 = (_Float16*)(ws + o); o = align256(o + (size_t)N * HID * 2);
  _Float16* wt1 = (_Float16*)(ws + o); o = align256(o + (size_t)HID * HID * 2);
  _Float16* wt2 = (_Float16*)(ws + o); o = align256(o + (size_t)HID * HID * 2);

  const int BS = 256;
  int gN = (N + BS - 1) / BS;
  int gN32 = (int)(((long long)N * 32 + BS - 1) / BS);
  int gW = (HID * HID + BS - 1) / BS;

  // ---- ELL build + normalization ----
  k_zero_cnt<<<gN, BS, 0, stream>>>(cnt, N);
  bool vec4ok = (E % 4 == 0) && (((uintptr_t)src & 15) == 0) && (((uintptr_t)dst & 15) == 0);
  if (vec4ok) {
    int E4 = E / 4;
    k_fill_ell4<<<(E4 + BS - 1) / BS, BS, 0, stream>>>((const int4*)src, (const int4*)dst,
                                                       cnt, ell, E4);
  } else {
    k_fill_ell1<<<(E + BS - 1) / BS, BS, 0, stream>>>(src, dst, cnt, ell, E);
  }
  k_dis<<<gN, BS, 0, stream>>>(cnt, dis, N);

  // ---- weight prep (fp16, transposed) ----
  k_prep_w16<<<gW, BS, 0, stream>>>(W1, wt1);
  k_prep_w16<<<gW, BS, 0, stream>>>(W2, wt2);

  // ---- layer 0: aggregate 3-dim x, then transform ----
  k_prep_x<<<gN, BS, 0, stream>>>(x, dis, x4, N);
  k_agg3<<<gN, BS, 0, stream>>>(x4, ell, cnt, dis, z4, N);
  k_gemm3b<<<gN32, BS, 0, stream>>>(z4, W0, b0, h16, N);

  // ---- layer 1 ----
  k_gemm16<<<(N + 63) / 64, 256, 0, stream>>>(h16, wt1, dis, g16, N);
  k_gather16<<<gN32, BS, 0, stream>>>(g16, ell, cnt, dis, b1, h16, N);

  // ---- layer 2 ----
  k_gemm16<<<(N + 63) / 64, 256, 0, stream>>>(h16, wt2, dis, g16, N);
  k_gather16<<<gN32, BS, 0, stream>>>(g16, ell, cnt, dis, b2, h16, N);

  // ---- fused pool + MLP ----
  k_pool_mlp<<<Gn, 256, 0, stream>>>(h16, batch, N, Wf1, bf1, Wf2, bf2, out);
}

// Round 7
// 376.296 us; speedup vs baseline: 2.2111x; 1.2654x over previous
//
#include <hip/hip_runtime.h>

#define HID 128
#define ELLW 64

// ---- binned ELL build params ----
#define NBINS 400          // buckets of 256 dst nodes; supports N <= 102400
#define BINCAP 38          // LDS bin capacity (mean ~21, 3.7 sigma; overflow -> ovf list)
#define CHUNK_I4 2048      // 8192 edges per block in pass A
#define BKCAP 5120         // global bucket capacity (mean ~4092, ~16 sigma)
#define OVF_CAP 16384

typedef _Float16 half8 __attribute__((ext_vector_type(8)));
typedef float f32x4 __attribute__((ext_vector_type(4)));
struct alignas(8) H4v { _Float16 x, y, z, w; };

// ---------------- pass A: bin edges by dst>>8 with LDS staging ----------------

__global__ void k_zero_ints(int* p, int n) {
  int i = blockIdx.x * blockDim.x + threadIdx.x;
  if (i < n) p[i] = 0;
}

__device__ __forceinline__ void bin_one(int s, int d, int* lcnt, unsigned* bins,
                                        int* ovfn, int2* ovf) {
  int b = d >> 8;
  int p = atomicAdd(&lcnt[b], 1);
  if (p < BINCAP) bins[b * BINCAP + p] = ((unsigned)s << 8) | (unsigned)(d & 255);
  else { int q = atomicAdd(ovfn, 1); if (q < OVF_CAP) ovf[q] = make_int2(s, d); }
}

__global__ __launch_bounds__(256) void k_binA(
    const int4* __restrict__ src4, const int4* __restrict__ dst4, int E4,
    int* bkcnt, unsigned* __restrict__ bk, int* ovfn, int2* __restrict__ ovf) {
  __shared__ unsigned bins[NBINS * BINCAP];
  __shared__ int lcnt[NBINS];
  __shared__ int gbase[NBINS];
  int t = threadIdx.x;
  for (int b = t; b < NBINS; b += 256) lcnt[b] = 0;
  __syncthreads();

  int i0 = blockIdx.x * CHUNK_I4;
  int i1 = min(i0 + CHUNK_I4, E4);
  for (int i = i0 + t; i < i1; i += 256) {
    int4 d = dst4[i];
    int4 s = src4[i];
    bin_one(s.x, d.x, lcnt, bins, ovfn, ovf);
    bin_one(s.y, d.y, lcnt, bins, ovfn, ovf);
    bin_one(s.z, d.z, lcnt, bins, ovfn, ovf);
    bin_one(s.w, d.w, lcnt, bins, ovfn, ovf);
  }
  __syncthreads();

  // reserve contiguous ranges: ONE global atomic per (block, bin)
  for (int b = t; b < NBINS; b += 256) gbase[b] = atomicAdd(&bkcnt[b], min(lcnt[b], BINCAP));
  __syncthreads();

  // flush bins as contiguous runs (wave-cooperative, coalesced)
  int wid = t >> 6, lane = t & 63;
  for (int b = wid; b < NBINS; b += 4) {
    int c = min(lcnt[b], BINCAP);
    if (lane < c) {
      int off = gbase[b] + lane;
      unsigned r = bins[b * BINCAP + lane];
      if (off < BKCAP) bk[(size_t)b * BKCAP + off] = r;
      else {
        int q = atomicAdd(ovfn, 1);
        if (q < OVF_CAP) ovf[q] = make_int2((int)(r >> 8), b * 256 + (int)(r & 255));
      }
    }
  }
}

// scalar tail edges (E % 4 != 0) go straight to the overflow list
__global__ void k_tail_ovf(const int* __restrict__ src, const int* __restrict__ dst,
                           int e0, int E, int* ovfn, int2* __restrict__ ovf) {
  int e = e0 + threadIdx.x;
  if (e < E) {
    int q = atomicAdd(ovfn, 1);
    if (q < OVF_CAP) ovf[q] = make_int2(src[e], dst[e]);
  }
}

// ---------------- pass B: per-bucket ELL build (LDS cursors, L2-local writes) --------

__global__ __launch_bounds__(256) void k_ell_build2(
    const unsigned* __restrict__ bk, const int* __restrict__ bkcnt,
    int* __restrict__ ell, int* __restrict__ cnt, int N) {
  int b = blockIdx.x;
  int t = threadIdx.x;
  __shared__ int lcnt[256];
  lcnt[t] = 0;
  __syncthreads();
  int n = bkcnt[b]; if (n > BKCAP) n = BKCAP;
  const unsigned* my = bk + (size_t)b * BKCAP;
  for (int k = t; k < n; k += 256) {
    unsigned r = my[k];
    int d0 = (int)(r & 255);
    int s = (int)(r >> 8);
    int p = atomicAdd(&lcnt[d0], 1);
    if (p < ELLW) ell[(size_t)(b * 256 + d0) * ELLW + p] = s;
  }
  __syncthreads();
  int node = b * 256 + t;
  if (node < N) cnt[node] = lcnt[t];
}

__global__ void k_ovf_build(const int2* __restrict__ ovf, const int* __restrict__ ovfn,
                            int* cnt, int* ell) {
  int n = *ovfn; if (n > OVF_CAP) n = OVF_CAP;
  for (int k = threadIdx.x; k < n; k += blockDim.x) {
    int2 e = ovf[k];
    int p = atomicAdd(&cnt[e.y], 1);
    if (p < ELLW) ell[(size_t)e.y * ELLW + p] = e.x;
  }
}

// ---------------- fallback direct fill (N > 102400) ----------------

__global__ void k_fill_ell1(const int* __restrict__ src, const int* __restrict__ dst,
                            int* cnt, int* ell, int E) {
  int e = blockIdx.x * blockDim.x + threadIdx.x;
  if (e < E) {
    int d = dst[e];
    int p = atomicAdd(&cnt[d], 1);
    if (p < ELLW) ell[(size_t)d * ELLW + p] = src[e];
  }
}

__global__ void k_dis(const int* __restrict__ cnt, float* dis, int N) {
  int i = blockIdx.x * blockDim.x + threadIdx.x;
  if (i < N) dis[i] = rsqrtf((float)(cnt[i] + 1));
}

// ---------------- layer 0: aggregate 3-dim x first, then transform ----------------

__global__ void k_prep_x(const float* __restrict__ x, const float* __restrict__ dis,
                         float4* __restrict__ x4, int N) {
  int i = blockIdx.x * blockDim.x + threadIdx.x;
  if (i >= N) return;
  float s = dis[i];
  x4[i] = make_float4(s * x[i * 3 + 0], s * x[i * 3 + 1], s * x[i * 3 + 2], 0.f);
}

__global__ void k_agg3(const float4* __restrict__ x4, const int* __restrict__ ell,
                       const int* __restrict__ cnt, const float* __restrict__ dis,
                       float4* __restrict__ z4, int N) {
  int i = blockIdx.x * blockDim.x + threadIdx.x;
  if (i >= N) return;
  float4 a = x4[i];  // self-loop
  int c = cnt[i]; if (c > ELLW) c = ELLW;
  const int* row = &ell[(size_t)i * ELLW];
  for (int k = 0; k < c; ++k) {
    float4 v = x4[row[k]];
    a.x += v.x; a.y += v.y; a.z += v.z;
  }
  float s = dis[i];
  z4[i] = make_float4(s * a.x, s * a.y, s * a.z, 0.f);
}

// h16[i,:] = relu(z4[i] @ W0 + b0)  (fp16 out)
__global__ void k_gemm3b(const float4* __restrict__ z4, const float* __restrict__ W0,
                         const float* __restrict__ b0, _Float16* __restrict__ h16, int N) {
  int tid = blockIdx.x * blockDim.x + threadIdx.x;
  int i = tid >> 5, q = tid & 31;
  if (i >= N) return;
  float4 z = z4[i];
  float4 w0 = *(const float4*)&W0[0 * HID + q * 4];
  float4 w1 = *(const float4*)&W0[1 * HID + q * 4];
  float4 w2 = *(const float4*)&W0[2 * HID + q * 4];
  float4 bb = *(const float4*)&b0[q * 4];
  H4v o;
  o.x = (_Float16)fmaxf(z.x * w0.x + z.y * w1.x + z.z * w2.x + bb.x, 0.f);
  o.y = (_Float16)fmaxf(z.x * w0.y + z.y * w1.y + z.z * w2.y + bb.y, 0.f);
  o.z = (_Float16)fmaxf(z.x * w0.z + z.y * w1.z + z.z * w2.z + bb.z, 0.f);
  o.w = (_Float16)fmaxf(z.x * w0.w + z.y * w1.w + z.z * w2.w + bb.w, 0.f);
  *(H4v*)&h16[(size_t)i * HID + q * 4] = o;
}

// ---------------- W -> fp16 transposed [n][k] ----------------

__global__ void k_prep_w16(const float* __restrict__ W, _Float16* __restrict__ Wt) {
  int idx = blockIdx.x * blockDim.x + threadIdx.x;
  if (idx >= HID * HID) return;
  int k = idx >> 7, n = idx & 127;
  Wt[n * HID + k] = (_Float16)W[idx];
}

// ---------------- MFMA GEMM: g16 = dis * (h16 @ W) ----------------

__global__ __launch_bounds__(256) void k_gemm16(
    const _Float16* __restrict__ H16, const _Float16* __restrict__ Wt16,
    const float* __restrict__ dis, _Float16* __restrict__ G16, int N) {
  int wid = threadIdx.x >> 6;
  int lane = threadIdx.x & 63;
  int m0 = blockIdx.x * 64 + wid * 16;
  int arow = m0 + (lane & 15);
  if (arow >= N) arow = N - 1;
  int kg = lane >> 4;

  f32x4 acc[8];
#pragma unroll
  for (int nt = 0; nt < 8; ++nt) acc[nt] = (f32x4){0.f, 0.f, 0.f, 0.f};

  const _Float16* ap = H16 + (size_t)arow * HID + kg * 8;
  const _Float16* bp = Wt16 + (size_t)(lane & 15) * HID + kg * 8;
#pragma unroll
  for (int kt = 0; kt < 4; ++kt) {
    half8 a = *(const half8*)(ap + kt * 32);
#pragma unroll
    for (int nt = 0; nt < 8; ++nt) {
      half8 b = *(const half8*)(bp + (size_t)nt * 16 * HID + kt * 32);
      acc[nt] = __builtin_amdgcn_mfma_f32_16x16x32_f16(a, b, acc[nt], 0, 0, 0);
    }
  }

  int ccol = lane & 15;
#pragma unroll
  for (int j = 0; j < 4; ++j) {
    int row = m0 + kg * 4 + j;
    if (row < N) {
      float s = dis[row];
#pragma unroll
      for (int nt = 0; nt < 8; ++nt) {
        G16[(size_t)row * HID + nt * 16 + ccol] = (_Float16)(s * acc[nt][j]);
      }
    }
  }
}

// ---------------- fused gather (fp16 payload) + finalize (fp16 out) ----------------

__global__ __launch_bounds__(256) void k_gather16(
    const _Float16* __restrict__ g16, const int* __restrict__ ell,
    const int* __restrict__ cnt, const float* __restrict__ dis,
    const float* __restrict__ b, _Float16* __restrict__ h16, int N) {
  int tid = blockIdx.x * blockDim.x + threadIdx.x;
  int i = tid >> 5, q = tid & 31;
  if (i >= N) return;
  H4v v0 = *(const H4v*)&g16[(size_t)i * HID + q * 4];  // self-loop
  float4 acc = make_float4((float)v0.x, (float)v0.y, (float)v0.z, (float)v0.w);
  int c = cnt[i]; if (c > ELLW) c = ELLW;
  const int* row = &ell[(size_t)i * ELLW];
  for (int k = 0; k < c; ++k) {
    int s = row[k];
    H4v v = *(const H4v*)&g16[(size_t)s * HID + q * 4];
    acc.x += (float)v.x; acc.y += (float)v.y; acc.z += (float)v.z; acc.w += (float)v.w;
  }
  float sc = dis[i];
  float4 bb = *(const float4*)&b[q * 4];
  H4v o;
  o.x = (_Float16)fmaxf(sc * acc.x + bb.x, 0.f);
  o.y = (_Float16)fmaxf(sc * acc.y + bb.y, 0.f);
  o.z = (_Float16)fmaxf(sc * acc.z + bb.z, 0.f);
  o.w = (_Float16)fmaxf(sc * acc.w + bb.w, 0.f);
  *(H4v*)&h16[(size_t)i * HID + q * 4] = o;
}

// ---------------- fused pool + MLP (batch sorted -> per-graph ranges) ----------------

__device__ __forceinline__ int lower_bound_i(const int* __restrict__ a, int n, int v) {
  int lo = 0, hi = n;
  while (lo < hi) {
    int m = (lo + hi) >> 1;
    if (a[m] < v) lo = m + 1; else hi = m;
  }
  return lo;
}

__global__ __launch_bounds__(256) void k_pool_mlp(
    const _Float16* __restrict__ h16, const int* __restrict__ batch, int N,
    const float* __restrict__ Wf1, const float* __restrict__ bf1,
    const float* __restrict__ Wf2, const float* __restrict__ bf2,
    float* __restrict__ out) {
  int g = blockIdx.x;
  int t = threadIdx.x;
  int lo = lower_bound_i(batch, N, g);
  int hi = lower_bound_i(batch, N, g + 1);

  __shared__ float4 part4[256];
  __shared__ float pooled[128];
  __shared__ float dense[64];

  int col4 = t & 31;
  int roff = t >> 5;
  float4 s = make_float4(0.f, 0.f, 0.f, 0.f);
  for (int r = lo + roff; r < hi; r += 8) {
    H4v v = *(const H4v*)&h16[(size_t)r * HID + col4 * 4];
    s.x += (float)v.x; s.y += (float)v.y; s.z += (float)v.z; s.w += (float)v.w;
  }
  part4[roff * 32 + col4] = s;
  __syncthreads();

  float inv = 1.0f / fmaxf((float)(hi - lo), 1.0f);
  if (t < 32) {
    float4 tot = part4[t];
#pragma unroll
    for (int j = 1; j < 8; ++j) {
      float4 v = part4[j * 32 + t];
      tot.x += v.x; tot.y += v.y; tot.z += v.z; tot.w += v.w;
    }
    pooled[t * 4 + 0] = tot.x * inv;
    pooled[t * 4 + 1] = tot.y * inv;
    pooled[t * 4 + 2] = tot.z * inv;
    pooled[t * 4 + 3] = tot.w * inv;
  }
  __syncthreads();

  if (t < 64) {
    float a = bf1[t];
    for (int k = 0; k < 128; ++k) a += pooled[k] * Wf1[k * 64 + t];
    dense[t] = fmaxf(a, 0.f);
  }
  __syncthreads();

  if (t < 64) {
    float prod = dense[t] * Wf2[t];
#pragma unroll
    for (int off = 32; off; off >>= 1) prod += __shfl_down(prod, off);
    if (t == 0) out[g] = prod + bf2[0];
  }
}

// ---------------- launch ----------------

static inline size_t align256(size_t x) { return (x + 255) & ~(size_t)255; }

extern "C" void kernel_launch(void* const* d_in, const int* in_sizes, int n_in,
                              void* d_out, int out_size, void* d_ws, size_t ws_size,
                              hipStream_t stream) {
  const float* x = (const float*)d_in[0];
  const int* ei = (const int*)d_in[1];
  const int* batch = (const int*)d_in[2];
  const float* W0 = (const float*)d_in[3];
  const float* b0 = (const float*)d_in[4];
  const float* W1 = (const float*)d_in[5];
  const float* b1 = (const float*)d_in[6];
  const float* W2 = (const float*)d_in[7];
  const float* b2 = (const float*)d_in[8];
  const float* Wf1 = (const float*)d_in[9];
  const float* bf1 = (const float*)d_in[10];
  const float* Wf2 = (const float*)d_in[11];
  const float* bf2 = (const float*)d_in[12];
  float* out = (float*)d_out;

  const int N = in_sizes[0] / 3;
  const int E = in_sizes[1] / 2;
  const int Gn = out_size;
  const int nbuk = (N + 255) >> 8;

  const int* src = ei;
  const int* dst = ei + E;

  char* ws = (char*)d_ws;
  size_t o = 0;
  int* cnt = (int*)(ws + o); o = align256(o + (size_t)N * 4);
  float* dis = (float*)(ws + o); o = align256(o + (size_t)N * 4);
  float4* x4 = (float4*)(ws + o); o = align256(o + (size_t)N * 16);
  float4* z4 = (float4*)(ws + o); o = align256(o + (size_t)N * 16);
  int* ell = (int*)(ws + o); o = align256(o + (size_t)N * ELLW * 4);
  _Float16* g16 = (_Float16*)(ws + o); o = align256(o + (size_t)N * HID * 2);
  _Float16* h16 = (_Float16*)(ws + o); o = align256(o + (size_t)N * HID * 2);
  _Float16* wt1 = (_Float16*)(ws + o); o = align256(o + (size_t)HID * HID * 2);
  _Float16* wt2 = (_Float16*)(ws + o); o = align256(o + (size_t)HID * HID * 2);
  int* bkcnt = (int*)(ws + o); o = align256(o + (size_t)(NBINS + 1) * 4);
  int* ovfn = bkcnt + NBINS;
  unsigned* bk = (unsigned*)(ws + o); o = align256(o + (size_t)NBINS * BKCAP * 4);
  int2* ovf = (int2*)(ws + o); o = align256(o + (size_t)OVF_CAP * 8);

  const int BS = 256;
  int gN = (N + BS - 1) / BS;
  int gN32 = (int)(((long long)N * 32 + BS - 1) / BS);
  int gW = (HID * HID + BS - 1) / BS;

  // ---- ELL build ----
  bool vec4ok = (E % 4 == 0) && (((uintptr_t)src & 15) == 0) && (((uintptr_t)dst & 15) == 0);
  if (nbuk <= NBINS) {
    k_zero_ints<<<(NBINS + 1 + BS - 1) / BS, BS, 0, stream>>>(bkcnt, NBINS + 1);
    int E4 = E / 4;
    if (E4 > 0 && vec4ok) {
      k_binA<<<(E4 + CHUNK_I4 - 1) / CHUNK_I4, 256, 0, stream>>>(
          (const int4*)src, (const int4*)dst, E4, bkcnt, bk, ovfn, ovf);
      if (E % 4) k_tail_ovf<<<1, 64, 0, stream>>>(src, dst, E4 * 4, E, ovfn, ovf);
    } else {
      k_tail_ovf<<<1, 256, 0, stream>>>(src, dst, 0, E, ovfn, ovf);  // degenerate path
    }
    k_ell_build2<<<nbuk, 256, 0, stream>>>(bk, bkcnt, ell, cnt, N);
    k_ovf_build<<<1, 256, 0, stream>>>(ovf, ovfn, cnt, ell);
  } else {
    // fallback: direct fill
    k_zero_ints<<<gN, BS, 0, stream>>>(cnt, N);
    k_fill_ell1<<<(E + BS - 1) / BS, BS, 0, stream>>>(src, dst, cnt, ell, E);
  }
  k_dis<<<gN, BS, 0, stream>>>(cnt, dis, N);

  // ---- weight prep (fp16, transposed) ----
  k_prep_w16<<<gW, BS, 0, stream>>>(W1, wt1);
  k_prep_w16<<<gW, BS, 0, stream>>>(W2, wt2);

  // ---- layer 0: aggregate 3-dim x, then transform ----
  k_prep_x<<<gN, BS, 0, stream>>>(x, dis, x4, N);
  k_agg3<<<gN, BS, 0, stream>>>(x4, ell, cnt, dis, z4, N);
  k_gemm3b<<<gN32, BS, 0, stream>>>(z4, W0, b0, h16, N);

  // ---- layer 1 ----
  k_gemm16<<<(N + 63) / 64, 256, 0, stream>>>(h16, wt1, dis, g16, N);
  k_gather16<<<gN32, BS, 0, stream>>>(g16, ell, cnt, dis, b1, h16, N);

  // ---- layer 2 ----
  k_gemm16<<<(N + 63) / 64, 256, 0, stream>>>(h16, wt2, dis, g16, N);
  k_gather16<<<gN32, BS, 0, stream>>>(g16, ell, cnt, dis, b2, h16, N);

  // ---- fused pool + MLP ----
  k_pool_mlp<<<Gn, 256, 0, stream>>>(h16, batch, N, Wf1, bf1, Wf2, bf2, out);
}

// Round 8
// 301.483 us; speedup vs baseline: 2.7598x; 1.2481x over previous
//
#include <hip/hip_runtime.h>

#define HID 128
#define ELLW 64

// ---- binned ELL build params ----
#define NBINS 400          // buckets of 256 dst nodes; supports N <= 102400
#define BINCAP 38          // LDS bin capacity
#define CHUNK_I4 1024      // 4096 edges per block in pass A
#define BKCAP 5120         // global bucket capacity
#define OVF_CAP 16384

typedef _Float16 half8 __attribute__((ext_vector_type(8)));
typedef float f32x4 __attribute__((ext_vector_type(4)));
struct alignas(8) H4v { _Float16 x, y, z, w; };

// ---------------- pass A: bin edges by dst>>8 with LDS staging ----------------

__global__ void k_zero_ints(int* p, int n) {
  int i = blockIdx.x * blockDim.x + threadIdx.x;
  if (i < n) p[i] = 0;
}

__device__ __forceinline__ void bin_one(int s, int d, int* lcnt, unsigned* bins,
                                        int* ovfn, int2* ovf) {
  int b = d >> 8;
  int p = atomicAdd(&lcnt[b], 1);
  if (p < BINCAP) bins[b * BINCAP + p] = ((unsigned)s << 8) | (unsigned)(d & 255);
  else { int q = atomicAdd(ovfn, 1); if (q < OVF_CAP) ovf[q] = make_int2(s, d); }
}

__global__ __launch_bounds__(256) void k_binA(
    const int4* __restrict__ src4, const int4* __restrict__ dst4, int E4,
    int* bkcnt, unsigned* __restrict__ bk, int* ovfn, int2* __restrict__ ovf) {
  __shared__ unsigned bins[NBINS * BINCAP];
  __shared__ int lcnt[NBINS];
  __shared__ int gbase[NBINS];
  int t = threadIdx.x;
  for (int b = t; b < NBINS; b += 256) lcnt[b] = 0;
  __syncthreads();

  int i0 = blockIdx.x * CHUNK_I4;
  int i1 = min(i0 + CHUNK_I4, E4);
  for (int i = i0 + t; i < i1; i += 256) {
    int4 d = dst4[i];
    int4 s = src4[i];
    bin_one(s.x, d.x, lcnt, bins, ovfn, ovf);
    bin_one(s.y, d.y, lcnt, bins, ovfn, ovf);
    bin_one(s.z, d.z, lcnt, bins, ovfn, ovf);
    bin_one(s.w, d.w, lcnt, bins, ovfn, ovf);
  }
  __syncthreads();

  for (int b = t; b < NBINS; b += 256) gbase[b] = atomicAdd(&bkcnt[b], min(lcnt[b], BINCAP));
  __syncthreads();

  int wid = t >> 6, lane = t & 63;
  for (int b = wid; b < NBINS; b += 4) {
    int c = min(lcnt[b], BINCAP);
    if (lane < c) {
      int off = gbase[b] + lane;
      unsigned r = bins[b * BINCAP + lane];
      if (off < BKCAP) bk[(size_t)b * BKCAP + off] = r;
      else {
        int q = atomicAdd(ovfn, 1);
        if (q < OVF_CAP) ovf[q] = make_int2((int)(r >> 8), b * 256 + (int)(r & 255));
      }
    }
  }
}

__global__ void k_tail_ovf(const int* __restrict__ src, const int* __restrict__ dst,
                           int e0, int E, int* ovfn, int2* __restrict__ ovf) {
  int e = e0 + threadIdx.x;
  if (e < E) {
    int q = atomicAdd(ovfn, 1);
    if (q < OVF_CAP) ovf[q] = make_int2(src[e], dst[e]);
  }
}

// ---------------- pass B: per-bucket ELL build ----------------

__global__ __launch_bounds__(256) void k_ell_build2(
    const unsigned* __restrict__ bk, const int* __restrict__ bkcnt,
    int* __restrict__ ell, int* __restrict__ cnt, int N) {
  int b = blockIdx.x;
  int t = threadIdx.x;
  __shared__ int lcnt[256];
  lcnt[t] = 0;
  __syncthreads();
  int n = bkcnt[b]; if (n > BKCAP) n = BKCAP;
  const unsigned* my = bk + (size_t)b * BKCAP;
  for (int k = t; k < n; k += 256) {
    unsigned r = my[k];
    int d0 = (int)(r & 255);
    int s = (int)(r >> 8);
    int p = atomicAdd(&lcnt[d0], 1);
    if (p < ELLW) ell[(size_t)(b * 256 + d0) * ELLW + p] = s;
  }
  __syncthreads();
  int node = b * 256 + t;
  if (node < N) cnt[node] = lcnt[t];
}

__global__ void k_ovf_build(const int2* __restrict__ ovf, const int* __restrict__ ovfn,
                            int* cnt, int* ell) {
  int n = *ovfn; if (n > OVF_CAP) n = OVF_CAP;
  for (int k = threadIdx.x; k < n; k += blockDim.x) {
    int2 e = ovf[k];
    int p = atomicAdd(&cnt[e.y], 1);
    if (p < ELLW) ell[(size_t)e.y * ELLW + p] = e.x;
  }
}

__global__ void k_fill_ell1(const int* __restrict__ src, const int* __restrict__ dst,
                            int* cnt, int* ell, int E) {
  int e = blockIdx.x * blockDim.x + threadIdx.x;
  if (e < E) {
    int d = dst[e];
    int p = atomicAdd(&cnt[d], 1);
    if (p < ELLW) ell[(size_t)d * ELLW + p] = src[e];
  }
}

__global__ void k_dis(const int* __restrict__ cnt, float* dis, int N) {
  int i = blockIdx.x * blockDim.x + threadIdx.x;
  if (i < N) dis[i] = rsqrtf((float)(cnt[i] + 1));
}

// ---------------- layer 0: aggregate 3-dim x first, then transform ----------------

__global__ void k_prep_x(const float* __restrict__ x, const float* __restrict__ dis,
                         float4* __restrict__ x4, int N) {
  int i = blockIdx.x * blockDim.x + threadIdx.x;
  if (i >= N) return;
  float s = dis[i];
  x4[i] = make_float4(s * x[i * 3 + 0], s * x[i * 3 + 1], s * x[i * 3 + 2], 0.f);
}

__global__ void k_agg3(const float4* __restrict__ x4, const int* __restrict__ ell,
                       const int* __restrict__ cnt, const float* __restrict__ dis,
                       float4* __restrict__ z4, int N) {
  int i = blockIdx.x * blockDim.x + threadIdx.x;
  if (i >= N) return;
  float4 a = x4[i];
  int c = cnt[i]; if (c > ELLW) c = ELLW;
  const int* row = &ell[(size_t)i * ELLW];
  for (int k = 0; k < c; ++k) {
    float4 v = x4[row[k]];
    a.x += v.x; a.y += v.y; a.z += v.z;
  }
  float s = dis[i];
  z4[i] = make_float4(s * a.x, s * a.y, s * a.z, 0.f);
}

__global__ void k_gemm3b(const float4* __restrict__ z4, const float* __restrict__ W0,
                         const float* __restrict__ b0, _Float16* __restrict__ h16, int N) {
  int tid = blockIdx.x * blockDim.x + threadIdx.x;
  int i = tid >> 5, q = tid & 31;
  if (i >= N) return;
  float4 z = z4[i];
  float4 w0 = *(const float4*)&W0[0 * HID + q * 4];
  float4 w1 = *(const float4*)&W0[1 * HID + q * 4];
  float4 w2 = *(const float4*)&W0[2 * HID + q * 4];
  float4 bb = *(const float4*)&b0[q * 4];
  H4v o;
  o.x = (_Float16)fmaxf(z.x * w0.x + z.y * w1.x + z.z * w2.x + bb.x, 0.f);
  o.y = (_Float16)fmaxf(z.x * w0.y + z.y * w1.y + z.z * w2.y + bb.y, 0.f);
  o.z = (_Float16)fmaxf(z.x * w0.z + z.y * w1.z + z.z * w2.z + bb.z, 0.f);
  o.w = (_Float16)fmaxf(z.x * w0.w + z.y * w1.w + z.z * w2.w + bb.w, 0.f);
  *(H4v*)&h16[(size_t)i * HID + q * 4] = o;
}

// ---------------- both weights -> fp16 transposed [n][k], one launch ----------------

__global__ void k_prep_w16x2(const float* __restrict__ W1, const float* __restrict__ W2,
                             _Float16* __restrict__ Wt1, _Float16* __restrict__ Wt2) {
  int idx = blockIdx.x * blockDim.x + threadIdx.x;  // over 2*128*128
  if (idx >= 2 * HID * HID) return;
  int which = idx >> 14;
  int r = idx & (HID * HID - 1);
  int k = r >> 7, n = r & 127;
  const float* W = which ? W2 : W1;
  _Float16* Wt = which ? Wt2 : Wt1;
  Wt[n * HID + k] = (_Float16)W[r];
}

// ---------------- MFMA GEMM: g16 = dis * (h16 @ W) ----------------

__global__ __launch_bounds__(256) void k_gemm16(
    const _Float16* __restrict__ H16, const _Float16* __restrict__ Wt16,
    const float* __restrict__ dis, _Float16* __restrict__ G16, int N) {
  int wid = threadIdx.x >> 6;
  int lane = threadIdx.x & 63;
  int m0 = blockIdx.x * 64 + wid * 16;
  int arow = m0 + (lane & 15);
  if (arow >= N) arow = N - 1;
  int kg = lane >> 4;

  f32x4 acc[8];
#pragma unroll
  for (int nt = 0; nt < 8; ++nt) acc[nt] = (f32x4){0.f, 0.f, 0.f, 0.f};

  const _Float16* ap = H16 + (size_t)arow * HID + kg * 8;
  const _Float16* bp = Wt16 + (size_t)(lane & 15) * HID + kg * 8;
#pragma unroll
  for (int kt = 0; kt < 4; ++kt) {
    half8 a = *(const half8*)(ap + kt * 32);
#pragma unroll
    for (int nt = 0; nt < 8; ++nt) {
      half8 b = *(const half8*)(bp + (size_t)nt * 16 * HID + kt * 32);
      acc[nt] = __builtin_amdgcn_mfma_f32_16x16x32_f16(a, b, acc[nt], 0, 0, 0);
    }
  }

  int ccol = lane & 15;
#pragma unroll
  for (int j = 0; j < 4; ++j) {
    int row = m0 + kg * 4 + j;
    if (row < N) {
      float s = dis[row];
#pragma unroll
      for (int nt = 0; nt < 8; ++nt) {
        G16[(size_t)row * HID + nt * 16 + ccol] = (_Float16)(s * acc[nt][j]);
      }
    }
  }
}

// ---------------- gather v2: 16 lanes/row, 16B/lane, edge loop unrolled x4 ----------

__global__ __launch_bounds__(256) void k_gather16v2(
    const _Float16* __restrict__ g16, const int* __restrict__ ell,
    const int* __restrict__ cnt, const float* __restrict__ dis,
    const float* __restrict__ b, _Float16* __restrict__ h16, int N) {
  int tid = blockIdx.x * blockDim.x + threadIdx.x;
  int i = tid >> 4;   // one row per 16 lanes
  int q = tid & 15;   // halves [q*8, q*8+8)
  if (i >= N) return;

  float acc[8];
  half8 sv = *(const half8*)(g16 + (size_t)i * HID + q * 8);  // self-loop
#pragma unroll
  for (int j = 0; j < 8; ++j) acc[j] = (float)sv[j];

  int c = cnt[i]; if (c > ELLW) c = ELLW;
  const int* row = ell + (size_t)i * ELLW;
  int k = 0;
  for (; k + 4 <= c; k += 4) {
    int4 s4 = *(const int4*)(row + k);
    half8 v0 = *(const half8*)(g16 + (size_t)s4.x * HID + q * 8);
    half8 v1 = *(const half8*)(g16 + (size_t)s4.y * HID + q * 8);
    half8 v2 = *(const half8*)(g16 + (size_t)s4.z * HID + q * 8);
    half8 v3 = *(const half8*)(g16 + (size_t)s4.w * HID + q * 8);
#pragma unroll
    for (int j = 0; j < 8; ++j)
      acc[j] += ((float)v0[j] + (float)v1[j]) + ((float)v2[j] + (float)v3[j]);
  }
  for (; k < c; ++k) {
    half8 v = *(const half8*)(g16 + (size_t)row[k] * HID + q * 8);
#pragma unroll
    for (int j = 0; j < 8; ++j) acc[j] += (float)v[j];
  }

  float sc = dis[i];
  half8 o;
#pragma unroll
  for (int j = 0; j < 8; ++j) {
    float bb = b[q * 8 + j];
    o[j] = (_Float16)fmaxf(sc * acc[j] + bb, 0.f);
  }
  *(half8*)(h16 + (size_t)i * HID + q * 8) = o;
}

// ---------------- fused pool + MLP ----------------

__device__ __forceinline__ int lower_bound_i(const int* __restrict__ a, int n, int v) {
  int lo = 0, hi = n;
  while (lo < hi) {
    int m = (lo + hi) >> 1;
    if (a[m] < v) lo = m + 1; else hi = m;
  }
  return lo;
}

__global__ __launch_bounds__(256) void k_pool_mlp(
    const _Float16* __restrict__ h16, const int* __restrict__ batch, int N,
    const float* __restrict__ Wf1, const float* __restrict__ bf1,
    const float* __restrict__ Wf2, const float* __restrict__ bf2,
    float* __restrict__ out) {
  int g = blockIdx.x;
  int t = threadIdx.x;
  int lo = lower_bound_i(batch, N, g);
  int hi = lower_bound_i(batch, N, g + 1);

  __shared__ float4 part4[256];
  __shared__ float pooled[128];
  __shared__ float dense[64];

  int col4 = t & 31;
  int roff = t >> 5;
  float4 s = make_float4(0.f, 0.f, 0.f, 0.f);
  for (int r = lo + roff; r < hi; r += 8) {
    H4v v = *(const H4v*)&h16[(size_t)r * HID + col4 * 4];
    s.x += (float)v.x; s.y += (float)v.y; s.z += (float)v.z; s.w += (float)v.w;
  }
  part4[roff * 32 + col4] = s;
  __syncthreads();

  float inv = 1.0f / fmaxf((float)(hi - lo), 1.0f);
  if (t < 32) {
    float4 tot = part4[t];
#pragma unroll
    for (int j = 1; j < 8; ++j) {
      float4 v = part4[j * 32 + t];
      tot.x += v.x; tot.y += v.y; tot.z += v.z; tot.w += v.w;
    }
    pooled[t * 4 + 0] = tot.x * inv;
    pooled[t * 4 + 1] = tot.y * inv;
    pooled[t * 4 + 2] = tot.z * inv;
    pooled[t * 4 + 3] = tot.w * inv;
  }
  __syncthreads();

  if (t < 64) {
    float a = bf1[t];
    for (int k = 0; k < 128; ++k) a += pooled[k] * Wf1[k * 64 + t];
    dense[t] = fmaxf(a, 0.f);
  }
  __syncthreads();

  if (t < 64) {
    float prod = dense[t] * Wf2[t];
#pragma unroll
    for (int off = 32; off; off >>= 1) prod += __shfl_down(prod, off);
    if (t == 0) out[g] = prod + bf2[0];
  }
}

// ---------------- launch ----------------

static inline size_t align256(size_t x) { return (x + 255) & ~(size_t)255; }

extern "C" void kernel_launch(void* const* d_in, const int* in_sizes, int n_in,
                              void* d_out, int out_size, void* d_ws, size_t ws_size,
                              hipStream_t stream) {
  const float* x = (const float*)d_in[0];
  const int* ei = (const int*)d_in[1];
  const int* batch = (const int*)d_in[2];
  const float* W0 = (const float*)d_in[3];
  const float* b0 = (const float*)d_in[4];
  const float* W1 = (const float*)d_in[5];
  const float* b1 = (const float*)d_in[6];
  const float* W2 = (const float*)d_in[7];
  const float* b2 = (const float*)d_in[8];
  const float* Wf1 = (const float*)d_in[9];
  const float* bf1 = (const float*)d_in[10];
  const float* Wf2 = (const float*)d_in[11];
  const float* bf2 = (const float*)d_in[12];
  float* out = (float*)d_out;

  const int N = in_sizes[0] / 3;
  const int E = in_sizes[1] / 2;
  const int Gn = out_size;
  const int nbuk = (N + 255) >> 8;

  const int* src = ei;
  const int* dst = ei + E;

  char* ws = (char*)d_ws;
  size_t o = 0;
  int* cnt = (int*)(ws + o); o = align256(o + (size_t)N * 4);
  float* dis = (float*)(ws + o); o = align256(o + (size_t)N * 4);
  float4* x4 = (float4*)(ws + o); o = align256(o + (size_t)N * 16);
  float4* z4 = (float4*)(ws + o); o = align256(o + (size_t)N * 16);
  int* ell = (int*)(ws + o); o = align256(o + (size_t)N * ELLW * 4);
  _Float16* g16 = (_Float16*)(ws + o); o = align256(o + (size_t)N * HID * 2);
  _Float16* h16 = (_Float16*)(ws + o); o = align256(o + (size_t)N * HID * 2);
  _Float16* wt1 = (_Float16*)(ws + o); o = align256(o + (size_t)HID * HID * 2);
  _Float16* wt2 = (_Float16*)(ws + o); o = align256(o + (size_t)HID * HID * 2);
  int* bkcnt = (int*)(ws + o); o = align256(o + (size_t)(NBINS + 1) * 4);
  int* ovfn = bkcnt + NBINS;
  unsigned* bk = (unsigned*)(ws + o); o = align256(o + (size_t)NBINS * BKCAP * 4);
  int2* ovf = (int2*)(ws + o); o = align256(o + (size_t)OVF_CAP * 8);

  const int BS = 256;
  int gN = (N + BS - 1) / BS;
  int gN16 = (int)(((long long)N * 16 + BS - 1) / BS);
  int gN32 = (int)(((long long)N * 32 + BS - 1) / BS);
  int gW2 = (2 * HID * HID + BS - 1) / BS;

  // ---- ELL build ----
  bool vec4ok = (E % 4 == 0) && (((uintptr_t)src & 15) == 0) && (((uintptr_t)dst & 15) == 0);
  if (nbuk <= NBINS) {
    k_zero_ints<<<(NBINS + 1 + BS - 1) / BS, BS, 0, stream>>>(bkcnt, NBINS + 1);
    int E4 = E / 4;
    if (E4 > 0 && vec4ok) {
      k_binA<<<(E4 + CHUNK_I4 - 1) / CHUNK_I4, 256, 0, stream>>>(
          (const int4*)src, (const int4*)dst, E4, bkcnt, bk, ovfn, ovf);
      if (E % 4) k_tail_ovf<<<1, 64, 0, stream>>>(src, dst, E4 * 4, E, ovfn, ovf);
    } else {
      k_tail_ovf<<<1, 256, 0, stream>>>(src, dst, 0, E, ovfn, ovf);
    }
    k_ell_build2<<<nbuk, 256, 0, stream>>>(bk, bkcnt, ell, cnt, N);
    k_ovf_build<<<1, 256, 0, stream>>>(ovf, ovfn, cnt, ell);
  } else {
    k_zero_ints<<<gN, BS, 0, stream>>>(cnt, N);
    k_fill_ell1<<<(E + BS - 1) / BS, BS, 0, stream>>>(src, dst, cnt, ell, E);
  }
  k_dis<<<gN, BS, 0, stream>>>(cnt, dis, N);

  // ---- weight prep ----
  k_prep_w16x2<<<gW2, BS, 0, stream>>>(W1, W2, wt1, wt2);

  // ---- layer 0 ----
  k_prep_x<<<gN, BS, 0, stream>>>(x, dis, x4, N);
  k_agg3<<<gN, BS, 0, stream>>>(x4, ell, cnt, dis, z4, N);
  k_gemm3b<<<gN32, BS, 0, stream>>>(z4, W0, b0, h16, N);

  // ---- layer 1 ----
  k_gemm16<<<(N + 63) / 64, 256, 0, stream>>>(h16, wt1, dis, g16, N);
  k_gather16v2<<<gN16, BS, 0, stream>>>(g16, ell, cnt, dis, b1, h16, N);

  // ---- layer 2 ----
  k_gemm16<<<(N + 63) / 64, 256, 0, stream>>>(h16, wt2, dis, g16, N);
  k_gather16v2<<<gN16, BS, 0, stream>>>(g16, ell, cnt, dis, b2, h16, N);

  // ---- fused pool + MLP ----
  k_pool_mlp<<<Gn, 256, 0, stream>>>(h16, batch, N, Wf1, bf1, Wf2, bf2, out);
}

// Round 9
// 298.559 us; speedup vs baseline: 2.7869x; 1.0098x over previous
//
#include <hip/hip_runtime.h>

#define HID 128
#define ELLW 64

// ---- binned ELL build params ----
#define NBINS 400          // buckets of 256 dst nodes; supports N <= 102400
#define BINCAP 38          // LDS bin capacity
#define CHUNK_I4 1024      // 4096 edges per block in pass A
#define BKCAP 5120         // global bucket capacity
#define OVF_CAP 16384

typedef _Float16 half8 __attribute__((ext_vector_type(8)));
typedef float f32x4 __attribute__((ext_vector_type(4)));
struct alignas(8) H4v { _Float16 x, y, z, w; };

// ---------------- pass A: bin edges by dst>>8 with LDS staging ----------------

__global__ void k_zero_ints(int* p, int n) {
  int i = blockIdx.x * blockDim.x + threadIdx.x;
  if (i < n) p[i] = 0;
}

__device__ __forceinline__ void bin_one(int s, int d, int* lcnt, unsigned* bins,
                                        int* ovfn, int2* ovf) {
  int b = d >> 8;
  int p = atomicAdd(&lcnt[b], 1);
  if (p < BINCAP) bins[b * BINCAP + p] = ((unsigned)s << 8) | (unsigned)(d & 255);
  else { int q = atomicAdd(ovfn, 1); if (q < OVF_CAP) ovf[q] = make_int2(s, d); }
}

__global__ __launch_bounds__(256) void k_binA(
    const int4* __restrict__ src4, const int4* __restrict__ dst4, int E4,
    int* bkcnt, unsigned* __restrict__ bk, int* ovfn, int2* __restrict__ ovf) {
  __shared__ unsigned bins[NBINS * BINCAP];
  __shared__ int lcnt[NBINS];
  __shared__ int gbase[NBINS];
  int t = threadIdx.x;
  for (int b = t; b < NBINS; b += 256) lcnt[b] = 0;
  __syncthreads();

  int i0 = blockIdx.x * CHUNK_I4;
  int i1 = min(i0 + CHUNK_I4, E4);
  for (int i = i0 + t; i < i1; i += 256) {
    int4 d = dst4[i];
    int4 s = src4[i];
    bin_one(s.x, d.x, lcnt, bins, ovfn, ovf);
    bin_one(s.y, d.y, lcnt, bins, ovfn, ovf);
    bin_one(s.z, d.z, lcnt, bins, ovfn, ovf);
    bin_one(s.w, d.w, lcnt, bins, ovfn, ovf);
  }
  __syncthreads();

  for (int b = t; b < NBINS; b += 256) gbase[b] = atomicAdd(&bkcnt[b], min(lcnt[b], BINCAP));
  __syncthreads();

  int wid = t >> 6, lane = t & 63;
  for (int b = wid; b < NBINS; b += 4) {
    int c = min(lcnt[b], BINCAP);
    if (lane < c) {
      int off = gbase[b] + lane;
      unsigned r = bins[b * BINCAP + lane];
      if (off < BKCAP) bk[(size_t)b * BKCAP + off] = r;
      else {
        int q = atomicAdd(ovfn, 1);
        if (q < OVF_CAP) ovf[q] = make_int2((int)(r >> 8), b * 256 + (int)(r & 255));
      }
    }
  }
}

__global__ void k_tail_ovf(const int* __restrict__ src, const int* __restrict__ dst,
                           int e0, int E, int* ovfn, int2* __restrict__ ovf) {
  int e = e0 + threadIdx.x;
  if (e < E) {
    int q = atomicAdd(ovfn, 1);
    if (q < OVF_CAP) ovf[q] = make_int2(src[e], dst[e]);
  }
}

// ---------------- pass B: per-bucket ELL build ----------------

__global__ __launch_bounds__(256) void k_ell_build2(
    const unsigned* __restrict__ bk, const int* __restrict__ bkcnt,
    int* __restrict__ ell, int* __restrict__ cnt, int N) {
  int b = blockIdx.x;
  int t = threadIdx.x;
  __shared__ int lcnt[256];
  lcnt[t] = 0;
  __syncthreads();
  int n = bkcnt[b]; if (n > BKCAP) n = BKCAP;
  const unsigned* my = bk + (size_t)b * BKCAP;
  for (int k = t; k < n; k += 256) {
    unsigned r = my[k];
    int d0 = (int)(r & 255);
    int s = (int)(r >> 8);
    int p = atomicAdd(&lcnt[d0], 1);
    if (p < ELLW) ell[(size_t)(b * 256 + d0) * ELLW + p] = s;
  }
  __syncthreads();
  int node = b * 256 + t;
  if (node < N) cnt[node] = lcnt[t];
}

__global__ void k_ovf_build(const int2* __restrict__ ovf, const int* __restrict__ ovfn,
                            int* cnt, int* ell) {
  int n = *ovfn; if (n > OVF_CAP) n = OVF_CAP;
  for (int k = threadIdx.x; k < n; k += blockDim.x) {
    int2 e = ovf[k];
    int p = atomicAdd(&cnt[e.y], 1);
    if (p < ELLW) ell[(size_t)e.y * ELLW + p] = e.x;
  }
}

__global__ void k_fill_ell1(const int* __restrict__ src, const int* __restrict__ dst,
                            int* cnt, int* ell, int E) {
  int e = blockIdx.x * blockDim.x + threadIdx.x;
  if (e < E) {
    int d = dst[e];
    int p = atomicAdd(&cnt[d], 1);
    if (p < ELLW) ell[(size_t)d * ELLW + p] = src[e];
  }
}

// ---------------- dis + prep_x fused: dis[i]=rsqrt(cnt+1); x4[i]=dis*x[i] -------------

__global__ void k_dis_prepx(const int* __restrict__ cnt, const float* __restrict__ x,
                            float* __restrict__ dis, float4* __restrict__ x4, int N) {
  int i = blockIdx.x * blockDim.x + threadIdx.x;
  if (i >= N) return;
  float s = rsqrtf((float)(cnt[i] + 1));
  dis[i] = s;
  x4[i] = make_float4(s * x[i * 3 + 0], s * x[i * 3 + 1], s * x[i * 3 + 2], 0.f);
}

// ---------------- layer 0 aggregate + transform ----------------

__global__ void k_agg3(const float4* __restrict__ x4, const int* __restrict__ ell,
                       const int* __restrict__ cnt, const float* __restrict__ dis,
                       float4* __restrict__ z4, int N) {
  int i = blockIdx.x * blockDim.x + threadIdx.x;
  if (i >= N) return;
  float4 a = x4[i];
  int c = cnt[i]; if (c > ELLW) c = ELLW;
  const int* row = &ell[(size_t)i * ELLW];
  for (int k = 0; k < c; ++k) {
    float4 v = x4[row[k]];
    a.x += v.x; a.y += v.y; a.z += v.z;
  }
  float s = dis[i];
  z4[i] = make_float4(s * a.x, s * a.y, s * a.z, 0.f);
}

__global__ void k_gemm3b(const float4* __restrict__ z4, const float* __restrict__ W0,
                         const float* __restrict__ b0, _Float16* __restrict__ h16, int N) {
  int tid = blockIdx.x * blockDim.x + threadIdx.x;
  int i = tid >> 5, q = tid & 31;
  if (i >= N) return;
  float4 z = z4[i];
  float4 w0 = *(const float4*)&W0[0 * HID + q * 4];
  float4 w1 = *(const float4*)&W0[1 * HID + q * 4];
  float4 w2 = *(const float4*)&W0[2 * HID + q * 4];
  float4 bb = *(const float4*)&b0[q * 4];
  H4v o;
  o.x = (_Float16)fmaxf(z.x * w0.x + z.y * w1.x + z.z * w2.x + bb.x, 0.f);
  o.y = (_Float16)fmaxf(z.x * w0.y + z.y * w1.y + z.z * w2.y + bb.y, 0.f);
  o.z = (_Float16)fmaxf(z.x * w0.z + z.y * w1.z + z.z * w2.z + bb.z, 0.f);
  o.w = (_Float16)fmaxf(z.x * w0.w + z.y * w1.w + z.z * w2.w + bb.w, 0.f);
  *(H4v*)&h16[(size_t)i * HID + q * 4] = o;
}

// ---------------- both weights -> fp16 transposed [n][k] ----------------

__global__ void k_prep_w16x2(const float* __restrict__ W1, const float* __restrict__ W2,
                             _Float16* __restrict__ Wt1, _Float16* __restrict__ Wt2) {
  int idx = blockIdx.x * blockDim.x + threadIdx.x;
  if (idx >= 2 * HID * HID) return;
  int which = idx >> 14;
  int r = idx & (HID * HID - 1);
  int k = r >> 7, n = r & 127;
  const float* W = which ? W2 : W1;
  _Float16* Wt = which ? Wt2 : Wt1;
  Wt[n * HID + k] = (_Float16)W[r];
}

// ---------------- MFMA GEMM: g16 = dis * (h16 @ W) ----------------

__global__ __launch_bounds__(256) void k_gemm16(
    const _Float16* __restrict__ H16, const _Float16* __restrict__ Wt16,
    const float* __restrict__ dis, _Float16* __restrict__ G16, int N) {
  int wid = threadIdx.x >> 6;
  int lane = threadIdx.x & 63;
  int m0 = blockIdx.x * 64 + wid * 16;
  int arow = m0 + (lane & 15);
  if (arow >= N) arow = N - 1;
  int kg = lane >> 4;

  f32x4 acc[8];
#pragma unroll
  for (int nt = 0; nt < 8; ++nt) acc[nt] = (f32x4){0.f, 0.f, 0.f, 0.f};

  const _Float16* ap = H16 + (size_t)arow * HID + kg * 8;
  const _Float16* bp = Wt16 + (size_t)(lane & 15) * HID + kg * 8;
#pragma unroll
  for (int kt = 0; kt < 4; ++kt) {
    half8 a = *(const half8*)(ap + kt * 32);
#pragma unroll
    for (int nt = 0; nt < 8; ++nt) {
      half8 b = *(const half8*)(bp + (size_t)nt * 16 * HID + kt * 32);
      acc[nt] = __builtin_amdgcn_mfma_f32_16x16x32_f16(a, b, acc[nt], 0, 0, 0);
    }
  }

  int ccol = lane & 15;
#pragma unroll
  for (int j = 0; j < 4; ++j) {
    int row = m0 + kg * 4 + j;
    if (row < N) {
      float s = dis[row];
#pragma unroll
      for (int nt = 0; nt < 8; ++nt) {
        G16[(size_t)row * HID + nt * 16 + ccol] = (_Float16)(s * acc[nt][j]);
      }
    }
  }
}

// ---------------- gather v3: 16 lanes/row, 16B/lane, edge loop unrolled x8 ----------

__global__ __launch_bounds__(256) void k_gather16v3(
    const _Float16* __restrict__ g16, const int* __restrict__ ell,
    const int* __restrict__ cnt, const float* __restrict__ dis,
    const float* __restrict__ b, _Float16* __restrict__ h16, int N) {
  int tid = blockIdx.x * blockDim.x + threadIdx.x;
  int i = tid >> 4;   // one row per 16 lanes
  int q = tid & 15;   // halves [q*8, q*8+8)
  if (i >= N) return;
  const _Float16* gq = g16 + q * 8;

  float acc[8];
  half8 sv = *(const half8*)(gq + (size_t)i * HID);  // self-loop
#pragma unroll
  for (int j = 0; j < 8; ++j) acc[j] = (float)sv[j];

  int c = cnt[i]; if (c > ELLW) c = ELLW;
  const int* row = ell + (size_t)i * ELLW;
  int k = 0;
  for (; k + 8 <= c; k += 8) {
    int4 sa = *(const int4*)(row + k);
    int4 sb = *(const int4*)(row + k + 4);
    half8 v0 = *(const half8*)(gq + (size_t)sa.x * HID);
    half8 v1 = *(const half8*)(gq + (size_t)sa.y * HID);
    half8 v2 = *(const half8*)(gq + (size_t)sa.z * HID);
    half8 v3 = *(const half8*)(gq + (size_t)sa.w * HID);
    half8 v4 = *(const half8*)(gq + (size_t)sb.x * HID);
    half8 v5 = *(const half8*)(gq + (size_t)sb.y * HID);
    half8 v6 = *(const half8*)(gq + (size_t)sb.z * HID);
    half8 v7 = *(const half8*)(gq + (size_t)sb.w * HID);
#pragma unroll
    for (int j = 0; j < 8; ++j) {
      float p01 = (float)v0[j] + (float)v1[j];
      float p23 = (float)v2[j] + (float)v3[j];
      float p45 = (float)v4[j] + (float)v5[j];
      float p67 = (float)v6[j] + (float)v7[j];
      acc[j] += (p01 + p23) + (p45 + p67);
    }
  }
  for (; k + 4 <= c; k += 4) {
    int4 s4 = *(const int4*)(row + k);
    half8 v0 = *(const half8*)(gq + (size_t)s4.x * HID);
    half8 v1 = *(const half8*)(gq + (size_t)s4.y * HID);
    half8 v2 = *(const half8*)(gq + (size_t)s4.z * HID);
    half8 v3 = *(const half8*)(gq + (size_t)s4.w * HID);
#pragma unroll
    for (int j = 0; j < 8; ++j)
      acc[j] += ((float)v0[j] + (float)v1[j]) + ((float)v2[j] + (float)v3[j]);
  }
  for (; k < c; ++k) {
    half8 v = *(const half8*)(gq + (size_t)row[k] * HID);
#pragma unroll
    for (int j = 0; j < 8; ++j) acc[j] += (float)v[j];
  }

  float sc = dis[i];
  half8 o;
#pragma unroll
  for (int j = 0; j < 8; ++j) {
    float bb = b[q * 8 + j];
    o[j] = (_Float16)fmaxf(sc * acc[j] + bb, 0.f);
  }
  *(half8*)(h16 + (size_t)i * HID + q * 8) = o;
}

// ---------------- fused pool + MLP ----------------

__device__ __forceinline__ int lower_bound_i(const int* __restrict__ a, int n, int v) {
  int lo = 0, hi = n;
  while (lo < hi) {
    int m = (lo + hi) >> 1;
    if (a[m] < v) lo = m + 1; else hi = m;
  }
  return lo;
}

__global__ __launch_bounds__(256) void k_pool_mlp(
    const _Float16* __restrict__ h16, const int* __restrict__ batch, int N,
    const float* __restrict__ Wf1, const float* __restrict__ bf1,
    const float* __restrict__ Wf2, const float* __restrict__ bf2,
    float* __restrict__ out) {
  int g = blockIdx.x;
  int t = threadIdx.x;
  int lo = lower_bound_i(batch, N, g);
  int hi = lower_bound_i(batch, N, g + 1);

  __shared__ float4 part4[256];
  __shared__ float pooled[128];
  __shared__ float dense[64];

  int col4 = t & 31;
  int roff = t >> 5;
  float4 s = make_float4(0.f, 0.f, 0.f, 0.f);
  for (int r = lo + roff; r < hi; r += 8) {
    H4v v = *(const H4v*)&h16[(size_t)r * HID + col4 * 4];
    s.x += (float)v.x; s.y += (float)v.y; s.z += (float)v.z; s.w += (float)v.w;
  }
  part4[roff * 32 + col4] = s;
  __syncthreads();

  float inv = 1.0f / fmaxf((float)(hi - lo), 1.0f);
  if (t < 32) {
    float4 tot = part4[t];
#pragma unroll
    for (int j = 1; j < 8; ++j) {
      float4 v = part4[j * 32 + t];
      tot.x += v.x; tot.y += v.y; tot.z += v.z; tot.w += v.w;
    }
    pooled[t * 4 + 0] = tot.x * inv;
    pooled[t * 4 + 1] = tot.y * inv;
    pooled[t * 4 + 2] = tot.z * inv;
    pooled[t * 4 + 3] = tot.w * inv;
  }
  __syncthreads();

  if (t < 64) {
    float a = bf1[t];
    for (int k = 0; k < 128; ++k) a += pooled[k] * Wf1[k * 64 + t];
    dense[t] = fmaxf(a, 0.f);
  }
  __syncthreads();

  if (t < 64) {
    float prod = dense[t] * Wf2[t];
#pragma unroll
    for (int off = 32; off; off >>= 1) prod += __shfl_down(prod, off);
    if (t == 0) out[g] = prod + bf2[0];
  }
}

// ---------------- launch ----------------

static inline size_t align256(size_t x) { return (x + 255) & ~(size_t)255; }

extern "C" void kernel_launch(void* const* d_in, const int* in_sizes, int n_in,
                              void* d_out, int out_size, void* d_ws, size_t ws_size,
                              hipStream_t stream) {
  const float* x = (const float*)d_in[0];
  const int* ei = (const int*)d_in[1];
  const int* batch = (const int*)d_in[2];
  const float* W0 = (const float*)d_in[3];
  const float* b0 = (const float*)d_in[4];
  const float* W1 = (const float*)d_in[5];
  const float* b1 = (const float*)d_in[6];
  const float* W2 = (const float*)d_in[7];
  const float* b2 = (const float*)d_in[8];
  const float* Wf1 = (const float*)d_in[9];
  const float* bf1 = (const float*)d_in[10];
  const float* Wf2 = (const float*)d_in[11];
  const float* bf2 = (const float*)d_in[12];
  float* out = (float*)d_out;

  const int N = in_sizes[0] / 3;
  const int E = in_sizes[1] / 2;
  const int Gn = out_size;
  const int nbuk = (N + 255) >> 8;

  const int* src = ei;
  const int* dst = ei + E;

  char* ws = (char*)d_ws;
  size_t o = 0;
  int* cnt = (int*)(ws + o); o = align256(o + (size_t)N * 4);
  float* dis = (float*)(ws + o); o = align256(o + (size_t)N * 4);
  float4* x4 = (float4*)(ws + o); o = align256(o + (size_t)N * 16);
  float4* z4 = (float4*)(ws + o); o = align256(o + (size_t)N * 16);
  int* ell = (int*)(ws + o); o = align256(o + (size_t)N * ELLW * 4);
  _Float16* g16 = (_Float16*)(ws + o); o = align256(o + (size_t)N * HID * 2);
  _Float16* h16 = (_Float16*)(ws + o); o = align256(o + (size_t)N * HID * 2);
  _Float16* wt1 = (_Float16*)(ws + o); o = align256(o + (size_t)HID * HID * 2);
  _Float16* wt2 = (_Float16*)(ws + o); o = align256(o + (size_t)HID * HID * 2);
  int* bkcnt = (int*)(ws + o); o = align256(o + (size_t)(NBINS + 1) * 4);
  int* ovfn = bkcnt + NBINS;
  unsigned* bk = (unsigned*)(ws + o); o = align256(o + (size_t)NBINS * BKCAP * 4);
  int2* ovf = (int2*)(ws + o); o = align256(o + (size_t)OVF_CAP * 8);

  const int BS = 256;
  int gN = (N + BS - 1) / BS;
  int gN16 = (int)(((long long)N * 16 + BS - 1) / BS);
  int gN32 = (int)(((long long)N * 32 + BS - 1) / BS);
  int gW2 = (2 * HID * HID + BS - 1) / BS;

  // ---- ELL build ----
  bool vec4ok = (E % 4 == 0) && (((uintptr_t)src & 15) == 0) && (((uintptr_t)dst & 15) == 0);
  if (nbuk <= NBINS) {
    k_zero_ints<<<(NBINS + 1 + BS - 1) / BS, BS, 0, stream>>>(bkcnt, NBINS + 1);
    int E4 = E / 4;
    if (E4 > 0 && vec4ok) {
      k_binA<<<(E4 + CHUNK_I4 - 1) / CHUNK_I4, 256, 0, stream>>>(
          (const int4*)src, (const int4*)dst, E4, bkcnt, bk, ovfn, ovf);
      if (E % 4) k_tail_ovf<<<1, 64, 0, stream>>>(src, dst, E4 * 4, E, ovfn, ovf);
    } else {
      k_tail_ovf<<<1, 256, 0, stream>>>(src, dst, 0, E, ovfn, ovf);
    }
    k_ell_build2<<<nbuk, 256, 0, stream>>>(bk, bkcnt, ell, cnt, N);
    k_ovf_build<<<1, 256, 0, stream>>>(ovf, ovfn, cnt, ell);
  } else {
    k_zero_ints<<<gN, BS, 0, stream>>>(cnt, N);
    k_fill_ell1<<<(E + BS - 1) / BS, BS, 0, stream>>>(src, dst, cnt, ell, E);
  }

  // ---- dis + x4 (fused) ----
  k_dis_prepx<<<gN, BS, 0, stream>>>(cnt, x, dis, x4, N);

  // ---- weight prep ----
  k_prep_w16x2<<<gW2, BS, 0, stream>>>(W1, W2, wt1, wt2);

  // ---- layer 0 ----
  k_agg3<<<gN, BS, 0, stream>>>(x4, ell, cnt, dis, z4, N);
  k_gemm3b<<<gN32, BS, 0, stream>>>(z4, W0, b0, h16, N);

  // ---- layer 1 ----
  k_gemm16<<<(N + 63) / 64, 256, 0, stream>>>(h16, wt1, dis, g16, N);
  k_gather16v3<<<gN16, BS, 0, stream>>>(g16, ell, cnt, dis, b1, h16, N);

  // ---- layer 2 ----
  k_gemm16<<<(N + 63) / 64, 256, 0, stream>>>(h16, wt2, dis, g16, N);
  k_gather16v3<<<gN16, BS, 0, stream>>>(g16, ell, cnt, dis, b2, h16, N);

  // ---- fused pool + MLP ----
  k_pool_mlp<<<Gn, 256, 0, stream>>>(h16, batch, N, Wf1, bf1, Wf2, bf2, out);
}

// Round 10
// 284.461 us; speedup vs baseline: 2.9250x; 1.0496x over previous
//
#include <hip/hip_runtime.h>

#define HID 128
#define ELLW 64

// ---- binned ELL build params ----
#define NBINS 400          // buckets of 256 dst nodes; supports N <= 102400
#define BINCAP 38          // LDS bin capacity
#define CHUNK_I4 1024      // 4096 edges per block in pass A
#define BKCAP 5120         // global bucket capacity
#define OVF_CAP 16384

typedef _Float16 half8 __attribute__((ext_vector_type(8)));
typedef float f32x4 __attribute__((ext_vector_type(4)));
struct alignas(8) H4v { _Float16 x, y, z, w; };

// ---------------- pass A: bin edges by dst>>8 with LDS staging ----------------

__global__ void k_zero_ints(int* p, int n) {
  int i = blockIdx.x * blockDim.x + threadIdx.x;
  if (i < n) p[i] = 0;
}

__device__ __forceinline__ void bin_one(int s, int d, int* lcnt, unsigned* bins,
                                        int* ovfn, int2* ovf) {
  int b = d >> 8;
  int p = atomicAdd(&lcnt[b], 1);
  if (p < BINCAP) bins[b * BINCAP + p] = ((unsigned)s << 8) | (unsigned)(d & 255);
  else { int q = atomicAdd(ovfn, 1); if (q < OVF_CAP) ovf[q] = make_int2(s, d); }
}

__global__ __launch_bounds__(256) void k_binA(
    const int4* __restrict__ src4, const int4* __restrict__ dst4, int E4,
    int* bkcnt, unsigned* __restrict__ bk, int* ovfn, int2* __restrict__ ovf) {
  __shared__ unsigned bins[NBINS * BINCAP];
  __shared__ int lcnt[NBINS];
  __shared__ int gbase[NBINS];
  int t = threadIdx.x;
  for (int b = t; b < NBINS; b += 256) lcnt[b] = 0;
  __syncthreads();

  int i0 = blockIdx.x * CHUNK_I4;
  int i1 = min(i0 + CHUNK_I4, E4);
  for (int i = i0 + t; i < i1; i += 256) {
    int4 d = dst4[i];
    int4 s = src4[i];
    bin_one(s.x, d.x, lcnt, bins, ovfn, ovf);
    bin_one(s.y, d.y, lcnt, bins, ovfn, ovf);
    bin_one(s.z, d.z, lcnt, bins, ovfn, ovf);
    bin_one(s.w, d.w, lcnt, bins, ovfn, ovf);
  }
  __syncthreads();

  for (int b = t; b < NBINS; b += 256) gbase[b] = atomicAdd(&bkcnt[b], min(lcnt[b], BINCAP));
  __syncthreads();

  int wid = t >> 6, lane = t & 63;
  for (int b = wid; b < NBINS; b += 4) {
    int c = min(lcnt[b], BINCAP);
    if (lane < c) {
      int off = gbase[b] + lane;
      unsigned r = bins[b * BINCAP + lane];
      if (off < BKCAP) bk[(size_t)b * BKCAP + off] = r;
      else {
        int q = atomicAdd(ovfn, 1);
        if (q < OVF_CAP) ovf[q] = make_int2((int)(r >> 8), b * 256 + (int)(r & 255));
      }
    }
  }
}

__global__ void k_tail_ovf(const int* __restrict__ src, const int* __restrict__ dst,
                           int e0, int E, int* ovfn, int2* __restrict__ ovf) {
  int e = e0 + threadIdx.x;
  if (e < E) {
    int q = atomicAdd(ovfn, 1);
    if (q < OVF_CAP) ovf[q] = make_int2(src[e], dst[e]);
  }
}

// ---------------- pass B: per-bucket ELL build ----------------

__global__ __launch_bounds__(256) void k_ell_build2(
    const unsigned* __restrict__ bk, const int* __restrict__ bkcnt,
    int* __restrict__ ell, int* __restrict__ cnt, int N) {
  int b = blockIdx.x;
  int t = threadIdx.x;
  __shared__ int lcnt[256];
  lcnt[t] = 0;
  __syncthreads();
  int n = bkcnt[b]; if (n > BKCAP) n = BKCAP;
  const unsigned* my = bk + (size_t)b * BKCAP;
  for (int k = t; k < n; k += 256) {
    unsigned r = my[k];
    int d0 = (int)(r & 255);
    int s = (int)(r >> 8);
    int p = atomicAdd(&lcnt[d0], 1);
    if (p < ELLW) ell[(size_t)(b * 256 + d0) * ELLW + p] = s;
  }
  __syncthreads();
  int node = b * 256 + t;
  if (node < N) cnt[node] = lcnt[t];
}

__global__ void k_ovf_build(const int2* __restrict__ ovf, const int* __restrict__ ovfn,
                            int* cnt, int* ell) {
  int n = *ovfn; if (n > OVF_CAP) n = OVF_CAP;
  for (int k = threadIdx.x; k < n; k += blockDim.x) {
    int2 e = ovf[k];
    int p = atomicAdd(&cnt[e.y], 1);
    if (p < ELLW) ell[(size_t)e.y * ELLW + p] = e.x;
  }
}

__global__ void k_fill_ell1(const int* __restrict__ src, const int* __restrict__ dst,
                            int* cnt, int* ell, int E) {
  int e = blockIdx.x * blockDim.x + threadIdx.x;
  if (e < E) {
    int d = dst[e];
    int p = atomicAdd(&cnt[d], 1);
    if (p < ELLW) ell[(size_t)d * ELLW + p] = src[e];
  }
}

// ---------------- dis + prep_x fused ----------------

__global__ void k_dis_prepx(const int* __restrict__ cnt, const float* __restrict__ x,
                            float* __restrict__ dis, float4* __restrict__ x4, int N) {
  int i = blockIdx.x * blockDim.x + threadIdx.x;
  if (i >= N) return;
  float s = rsqrtf((float)(cnt[i] + 1));
  dis[i] = s;
  x4[i] = make_float4(s * x[i * 3 + 0], s * x[i * 3 + 1], s * x[i * 3 + 2], 0.f);
}

// ---------------- layer 0 aggregate (unrolled x4) ----------------

__global__ void k_agg3(const float4* __restrict__ x4, const int* __restrict__ ell,
                       const int* __restrict__ cnt, const float* __restrict__ dis,
                       float4* __restrict__ z4, int N) {
  int i = blockIdx.x * blockDim.x + threadIdx.x;
  if (i >= N) return;
  float4 a = x4[i];
  int c = cnt[i]; if (c > ELLW) c = ELLW;
  const int* row = &ell[(size_t)i * ELLW];
  int k = 0;
  for (; k + 4 <= c; k += 4) {
    int4 s4 = *(const int4*)(row + k);
    float4 v0 = x4[s4.x], v1 = x4[s4.y], v2 = x4[s4.z], v3 = x4[s4.w];
    a.x += (v0.x + v1.x) + (v2.x + v3.x);
    a.y += (v0.y + v1.y) + (v2.y + v3.y);
    a.z += (v0.z + v1.z) + (v2.z + v3.z);
  }
  for (; k < c; ++k) {
    float4 v = x4[row[k]];
    a.x += v.x; a.y += v.y; a.z += v.z;
  }
  float s = dis[i];
  z4[i] = make_float4(s * a.x, s * a.y, s * a.z, 0.f);
}

// ---------------- both weights -> fp16 transposed [n][k] ----------------

__global__ void k_prep_w16x2(const float* __restrict__ W1, const float* __restrict__ W2,
                             _Float16* __restrict__ Wt1, _Float16* __restrict__ Wt2) {
  int idx = blockIdx.x * blockDim.x + threadIdx.x;
  if (idx >= 2 * HID * HID) return;
  int which = idx >> 14;
  int r = idx & (HID * HID - 1);
  int k = r >> 7, n = r & 127;
  const float* W = which ? W2 : W1;
  _Float16* Wt = which ? Wt2 : Wt1;
  Wt[n * HID + k] = (_Float16)W[r];
}

// ---------------- fused layer0-transform + layer1-GEMM ----------------
// per 64-row block: h = relu(z4@W0 + b0) -> LDS(fp16); then g16a = dis * (h @ W1)

__global__ __launch_bounds__(256) void k_l01(
    const float4* __restrict__ z4, const float* __restrict__ W0,
    const float* __restrict__ b0, const _Float16* __restrict__ wt1,
    const float* __restrict__ dis, _Float16* __restrict__ G, int N) {
  __shared__ _Float16 hs[64][136];   // padded: 272B rows -> 2-way banks only
  int t = threadIdx.x;
  int base = blockIdx.x * 64;

  // compute phase: 4 threads per row, 32 cols each
  {
    int r = t >> 2;
    int c0 = (t & 3) * 32;
    int row = base + r;
    float4 z = make_float4(0.f, 0.f, 0.f, 0.f);
    if (row < N) z = z4[row];
#pragma unroll
    for (int c = 0; c < 32; c += 4) {
      int cc = c0 + c;
      float4 w0 = *(const float4*)&W0[0 * HID + cc];
      float4 w1 = *(const float4*)&W0[1 * HID + cc];
      float4 w2 = *(const float4*)&W0[2 * HID + cc];
      float4 bb = *(const float4*)&b0[cc];
      H4v o;
      o.x = (_Float16)fmaxf(z.x * w0.x + z.y * w1.x + z.z * w2.x + bb.x, 0.f);
      o.y = (_Float16)fmaxf(z.x * w0.y + z.y * w1.y + z.z * w2.y + bb.y, 0.f);
      o.z = (_Float16)fmaxf(z.x * w0.z + z.y * w1.z + z.z * w2.z + bb.z, 0.f);
      o.w = (_Float16)fmaxf(z.x * w0.w + z.y * w1.w + z.z * w2.w + bb.w, 0.f);
      *(H4v*)&hs[r][cc] = o;
    }
  }
  __syncthreads();

  // MFMA phase: wave w -> rows [base + w*16, +16), all 128 cols
  int w = t >> 6, lane = t & 63;
  int kg = lane >> 4, ccol = lane & 15;
  int lrow = w * 16 + ccol;

  f32x4 acc[8];
#pragma unroll
  for (int nt = 0; nt < 8; ++nt) acc[nt] = (f32x4){0.f, 0.f, 0.f, 0.f};

#pragma unroll
  for (int kt = 0; kt < 4; ++kt) {
    half8 a = *(const half8*)&hs[lrow][kg * 8 + kt * 32];
#pragma unroll
    for (int nt = 0; nt < 8; ++nt) {
      half8 b = *(const half8*)(wt1 + (size_t)(nt * 16 + ccol) * HID + kg * 8 + kt * 32);
      acc[nt] = __builtin_amdgcn_mfma_f32_16x16x32_f16(a, b, acc[nt], 0, 0, 0);
    }
  }

#pragma unroll
  for (int j = 0; j < 4; ++j) {
    int row = base + w * 16 + kg * 4 + j;
    if (row < N) {
      float s = dis[row];
#pragma unroll
      for (int nt = 0; nt < 8; ++nt) {
        G[(size_t)row * HID + nt * 16 + ccol] = (_Float16)(s * acc[nt][j]);
      }
    }
  }
}

// ---------------- fused gather + layer2-GEMM ----------------
// per 16-row block: gather (v3 body, one row per 16-lane group) -> h in LDS;
// then g16b = dis * (h @ W2)

__global__ __launch_bounds__(256) void k_gg(
    const _Float16* __restrict__ Gin, const int* __restrict__ ell,
    const int* __restrict__ cnt, const float* __restrict__ dis,
    const float* __restrict__ b, const _Float16* __restrict__ wt2,
    _Float16* __restrict__ Gout, int N) {
  __shared__ _Float16 hs[16][136];
  int t = threadIdx.x;
  int base = blockIdx.x * 16;
  int gi = t >> 4, q = t & 15;
  int i = base + gi;

  if (i < N) {
    const _Float16* gq = Gin + q * 8;
    float acc[8];
    half8 sv = *(const half8*)(gq + (size_t)i * HID);  // self-loop
#pragma unroll
    for (int j = 0; j < 8; ++j) acc[j] = (float)sv[j];

    int c = cnt[i]; if (c > ELLW) c = ELLW;
    const int* row = ell + (size_t)i * ELLW;
    int k = 0;
    for (; k + 8 <= c; k += 8) {
      int4 sa = *(const int4*)(row + k);
      int4 sb = *(const int4*)(row + k + 4);
      half8 v0 = *(const half8*)(gq + (size_t)sa.x * HID);
      half8 v1 = *(const half8*)(gq + (size_t)sa.y * HID);
      half8 v2 = *(const half8*)(gq + (size_t)sa.z * HID);
      half8 v3 = *(const half8*)(gq + (size_t)sa.w * HID);
      half8 v4 = *(const half8*)(gq + (size_t)sb.x * HID);
      half8 v5 = *(const half8*)(gq + (size_t)sb.y * HID);
      half8 v6 = *(const half8*)(gq + (size_t)sb.z * HID);
      half8 v7 = *(const half8*)(gq + (size_t)sb.w * HID);
#pragma unroll
      for (int j = 0; j < 8; ++j) {
        float p01 = (float)v0[j] + (float)v1[j];
        float p23 = (float)v2[j] + (float)v3[j];
        float p45 = (float)v4[j] + (float)v5[j];
        float p67 = (float)v6[j] + (float)v7[j];
        acc[j] += (p01 + p23) + (p45 + p67);
      }
    }
    for (; k + 4 <= c; k += 4) {
      int4 s4 = *(const int4*)(row + k);
      half8 v0 = *(const half8*)(gq + (size_t)s4.x * HID);
      half8 v1 = *(const half8*)(gq + (size_t)s4.y * HID);
      half8 v2 = *(const half8*)(gq + (size_t)s4.z * HID);
      half8 v3 = *(const half8*)(gq + (size_t)s4.w * HID);
#pragma unroll
      for (int j = 0; j < 8; ++j)
        acc[j] += ((float)v0[j] + (float)v1[j]) + ((float)v2[j] + (float)v3[j]);
    }
    for (; k < c; ++k) {
      half8 v = *(const half8*)(gq + (size_t)row[k] * HID);
#pragma unroll
      for (int j = 0; j < 8; ++j) acc[j] += (float)v[j];
    }

    float sc = dis[i];
    half8 o;
#pragma unroll
    for (int j = 0; j < 8; ++j) {
      float bb = b[q * 8 + j];
      o[j] = (_Float16)fmaxf(sc * acc[j] + bb, 0.f);
    }
    *(half8*)&hs[gi][q * 8] = o;
  } else {
    half8 zo;
#pragma unroll
    for (int j = 0; j < 8; ++j) zo[j] = (_Float16)0.f;
    *(half8*)&hs[gi][q * 8] = zo;
  }
  __syncthreads();

  // MFMA: wave w covers col-tiles {2w, 2w+1}
  int w = t >> 6, lane = t & 63;
  int kg = lane >> 4, ccol = lane & 15;
  f32x4 acc2[2];
  acc2[0] = (f32x4){0.f, 0.f, 0.f, 0.f};
  acc2[1] = (f32x4){0.f, 0.f, 0.f, 0.f};

#pragma unroll
  for (int kt = 0; kt < 4; ++kt) {
    half8 a = *(const half8*)&hs[ccol][kg * 8 + kt * 32];
#pragma unroll
    for (int ntl = 0; ntl < 2; ++ntl) {
      int n = (2 * w + ntl) * 16 + ccol;
      half8 bf = *(const half8*)(wt2 + (size_t)n * HID + kg * 8 + kt * 32);
      acc2[ntl] = __builtin_amdgcn_mfma_f32_16x16x32_f16(a, bf, acc2[ntl], 0, 0, 0);
    }
  }

#pragma unroll
  for (int j = 0; j < 4; ++j) {
    int row = base + kg * 4 + j;
    if (row < N) {
      float s = dis[row];
#pragma unroll
      for (int ntl = 0; ntl < 2; ++ntl) {
        Gout[(size_t)row * HID + (2 * w + ntl) * 16 + ccol] = (_Float16)(s * acc2[ntl][j]);
      }
    }
  }
}

// ---------------- gather v3 (final layer: writes h) ----------------

__global__ __launch_bounds__(256) void k_gather16v3(
    const _Float16* __restrict__ g16, const int* __restrict__ ell,
    const int* __restrict__ cnt, const float* __restrict__ dis,
    const float* __restrict__ b, _Float16* __restrict__ h16, int N) {
  int tid = blockIdx.x * blockDim.x + threadIdx.x;
  int i = tid >> 4;
  int q = tid & 15;
  if (i >= N) return;
  const _Float16* gq = g16 + q * 8;

  float acc[8];
  half8 sv = *(const half8*)(gq + (size_t)i * HID);
#pragma unroll
  for (int j = 0; j < 8; ++j) acc[j] = (float)sv[j];

  int c = cnt[i]; if (c > ELLW) c = ELLW;
  const int* row = ell + (size_t)i * ELLW;
  int k = 0;
  for (; k + 8 <= c; k += 8) {
    int4 sa = *(const int4*)(row + k);
    int4 sb = *(const int4*)(row + k + 4);
    half8 v0 = *(const half8*)(gq + (size_t)sa.x * HID);
    half8 v1 = *(const half8*)(gq + (size_t)sa.y * HID);
    half8 v2 = *(const half8*)(gq + (size_t)sa.z * HID);
    half8 v3 = *(const half8*)(gq + (size_t)sa.w * HID);
    half8 v4 = *(const half8*)(gq + (size_t)sb.x * HID);
    half8 v5 = *(const half8*)(gq + (size_t)sb.y * HID);
    half8 v6 = *(const half8*)(gq + (size_t)sb.z * HID);
    half8 v7 = *(const half8*)(gq + (size_t)sb.w * HID);
#pragma unroll
    for (int j = 0; j < 8; ++j) {
      float p01 = (float)v0[j] + (float)v1[j];
      float p23 = (float)v2[j] + (float)v3[j];
      float p45 = (float)v4[j] + (float)v5[j];
      float p67 = (float)v6[j] + (float)v7[j];
      acc[j] += (p01 + p23) + (p45 + p67);
    }
  }
  for (; k + 4 <= c; k += 4) {
    int4 s4 = *(const int4*)(row + k);
    half8 v0 = *(const half8*)(gq + (size_t)s4.x * HID);
    half8 v1 = *(const half8*)(gq + (size_t)s4.y * HID);
    half8 v2 = *(const half8*)(gq + (size_t)s4.z * HID);
    half8 v3 = *(const half8*)(gq + (size_t)s4.w * HID);
#pragma unroll
    for (int j = 0; j < 8; ++j)
      acc[j] += ((float)v0[j] + (float)v1[j]) + ((float)v2[j] + (float)v3[j]);
  }
  for (; k < c; ++k) {
    half8 v = *(const half8*)(gq + (size_t)row[k] * HID);
#pragma unroll
    for (int j = 0; j < 8; ++j) acc[j] += (float)v[j];
  }

  float sc = dis[i];
  half8 o;
#pragma unroll
  for (int j = 0; j < 8; ++j) {
    float bb = b[q * 8 + j];
    o[j] = (_Float16)fmaxf(sc * acc[j] + bb, 0.f);
  }
  *(half8*)(h16 + (size_t)i * HID + q * 8) = o;
}

// ---------------- fused pool + MLP ----------------

__device__ __forceinline__ int lower_bound_i(const int* __restrict__ a, int n, int v) {
  int lo = 0, hi = n;
  while (lo < hi) {
    int m = (lo + hi) >> 1;
    if (a[m] < v) lo = m + 1; else hi = m;
  }
  return lo;
}

__global__ __launch_bounds__(256) void k_pool_mlp(
    const _Float16* __restrict__ h16, const int* __restrict__ batch, int N,
    const float* __restrict__ Wf1, const float* __restrict__ bf1,
    const float* __restrict__ Wf2, const float* __restrict__ bf2,
    float* __restrict__ out) {
  int g = blockIdx.x;
  int t = threadIdx.x;
  int lo = lower_bound_i(batch, N, g);
  int hi = lower_bound_i(batch, N, g + 1);

  __shared__ float4 part4[256];
  __shared__ float pooled[128];
  __shared__ float dense[64];

  int col4 = t & 31;
  int roff = t >> 5;
  float4 s = make_float4(0.f, 0.f, 0.f, 0.f);
  for (int r = lo + roff; r < hi; r += 8) {
    H4v v = *(const H4v*)&h16[(size_t)r * HID + col4 * 4];
    s.x += (float)v.x; s.y += (float)v.y; s.z += (float)v.z; s.w += (float)v.w;
  }
  part4[roff * 32 + col4] = s;
  __syncthreads();

  float inv = 1.0f / fmaxf((float)(hi - lo), 1.0f);
  if (t < 32) {
    float4 tot = part4[t];
#pragma unroll
    for (int j = 1; j < 8; ++j) {
      float4 v = part4[j * 32 + t];
      tot.x += v.x; tot.y += v.y; tot.z += v.z; tot.w += v.w;
    }
    pooled[t * 4 + 0] = tot.x * inv;
    pooled[t * 4 + 1] = tot.y * inv;
    pooled[t * 4 + 2] = tot.z * inv;
    pooled[t * 4 + 3] = tot.w * inv;
  }
  __syncthreads();

  if (t < 64) {
    float a = bf1[t];
    for (int k = 0; k < 128; ++k) a += pooled[k] * Wf1[k * 64 + t];
    dense[t] = fmaxf(a, 0.f);
  }
  __syncthreads();

  if (t < 64) {
    float prod = dense[t] * Wf2[t];
#pragma unroll
    for (int off = 32; off; off >>= 1) prod += __shfl_down(prod, off);
    if (t == 0) out[g] = prod + bf2[0];
  }
}

// ---------------- launch ----------------

static inline size_t align256(size_t x) { return (x + 255) & ~(size_t)255; }

extern "C" void kernel_launch(void* const* d_in, const int* in_sizes, int n_in,
                              void* d_out, int out_size, void* d_ws, size_t ws_size,
                              hipStream_t stream) {
  const float* x = (const float*)d_in[0];
  const int* ei = (const int*)d_in[1];
  const int* batch = (const int*)d_in[2];
  const float* W0 = (const float*)d_in[3];
  const float* b0 = (const float*)d_in[4];
  const float* W1 = (const float*)d_in[5];
  const float* b1 = (const float*)d_in[6];
  const float* W2 = (const float*)d_in[7];
  const float* b2 = (const float*)d_in[8];
  const float* Wf1 = (const float*)d_in[9];
  const float* bf1 = (const float*)d_in[10];
  const float* Wf2 = (const float*)d_in[11];
  const float* bf2 = (const float*)d_in[12];
  float* out = (float*)d_out;

  const int N = in_sizes[0] / 3;
  const int E = in_sizes[1] / 2;
  const int Gn = out_size;
  const int nbuk = (N + 255) >> 8;

  const int* src = ei;
  const int* dst = ei + E;

  char* ws = (char*)d_ws;
  size_t o = 0;
  int* cnt = (int*)(ws + o); o = align256(o + (size_t)N * 4);
  float* dis = (float*)(ws + o); o = align256(o + (size_t)N * 4);
  float4* x4 = (float4*)(ws + o); o = align256(o + (size_t)N * 16);
  float4* z4 = (float4*)(ws + o); o = align256(o + (size_t)N * 16);
  int* ell = (int*)(ws + o); o = align256(o + (size_t)N * ELLW * 4);
  _Float16* g16a = (_Float16*)(ws + o); o = align256(o + (size_t)N * HID * 2);
  _Float16* g16b = (_Float16*)(ws + o); o = align256(o + (size_t)N * HID * 2);
  _Float16* wt1 = (_Float16*)(ws + o); o = align256(o + (size_t)HID * HID * 2);
  _Float16* wt2 = (_Float16*)(ws + o); o = align256(o + (size_t)HID * HID * 2);
  int* bkcnt = (int*)(ws + o); o = align256(o + (size_t)(NBINS + 1) * 4);
  int* ovfn = bkcnt + NBINS;
  unsigned* bk = (unsigned*)(ws + o); o = align256(o + (size_t)NBINS * BKCAP * 4);
  int2* ovf = (int2*)(ws + o); o = align256(o + (size_t)OVF_CAP * 8);

  const int BS = 256;
  int gN = (N + BS - 1) / BS;
  int gN16 = (int)(((long long)N * 16 + BS - 1) / BS);
  int gW2 = (2 * HID * HID + BS - 1) / BS;

  // ---- ELL build ----
  bool vec4ok = (E % 4 == 0) && (((uintptr_t)src & 15) == 0) && (((uintptr_t)dst & 15) == 0);
  if (nbuk <= NBINS) {
    k_zero_ints<<<(NBINS + 1 + BS - 1) / BS, BS, 0, stream>>>(bkcnt, NBINS + 1);
    int E4 = E / 4;
    if (E4 > 0 && vec4ok) {
      k_binA<<<(E4 + CHUNK_I4 - 1) / CHUNK_I4, 256, 0, stream>>>(
          (const int4*)src, (const int4*)dst, E4, bkcnt, bk, ovfn, ovf);
      if (E % 4) k_tail_ovf<<<1, 64, 0, stream>>>(src, dst, E4 * 4, E, ovfn, ovf);
    } else {
      k_tail_ovf<<<1, 256, 0, stream>>>(src, dst, 0, E, ovfn, ovf);
    }
    k_ell_build2<<<nbuk, 256, 0, stream>>>(bk, bkcnt, ell, cnt, N);
    k_ovf_build<<<1, 256, 0, stream>>>(ovf, ovfn, cnt, ell);
  } else {
    k_zero_ints<<<gN, BS, 0, stream>>>(cnt, N);
    k_fill_ell1<<<(E + BS - 1) / BS, BS, 0, stream>>>(src, dst, cnt, ell, E);
  }

  // ---- dis + x4 ----
  k_dis_prepx<<<gN, BS, 0, stream>>>(cnt, x, dis, x4, N);

  // ---- weight prep ----
  k_prep_w16x2<<<gW2, BS, 0, stream>>>(W1, W2, wt1, wt2);

  // ---- layer 0 aggregate ----
  k_agg3<<<gN, BS, 0, stream>>>(x4, ell, cnt, dis, z4, N);

  // ---- fused: h0 = relu(z4@W0+b0); g16a = dis * (h0 @ W1) ----
  k_l01<<<(N + 63) / 64, 256, 0, stream>>>(z4, W0, b0, wt1, dis, g16a, N);

  // ---- fused: gather(g16a) -> h1; g16b = dis * (h1 @ W2) ----
  k_gg<<<(N + 15) / 16, 256, 0, stream>>>(g16a, ell, cnt, dis, b1, wt2, g16b, N);

  // ---- final gather: h2 -> g16a (reused as h buffer) ----
  k_gather16v3<<<gN16, BS, 0, stream>>>(g16b, ell, cnt, dis, b2, g16a, N);

  // ---- fused pool + MLP ----
  k_pool_mlp<<<Gn, 256, 0, stream>>>(g16a, batch, N, Wf1, bf1, Wf2, bf2, out);
}